// Round 6
// baseline (389.946 us; speedup 1.0000x reference)
//
#include <hip/hip_runtime.h>
#include <cmath>
#include <cstdint>
#include <cstddef>

typedef unsigned long long u64;
typedef unsigned int u32;

#define NPX   2500
#define NANCH 22500
#define PRE_TOPK 10000
#define NWORDS 160      // 160*64 = 10240 bits per NMS row

struct AnchorBase { float b[36]; };

typedef __attribute__((ext_vector_type(8))) short bf16x8;
typedef __attribute__((ext_vector_type(4))) float f32x4;

__device__ inline unsigned short f2bf(float f) {
    u32 u = __float_as_uint(f);
    u32 r = u + 0x7fffu + ((u >> 16) & 1u);
    return (unsigned short)(r >> 16);
}
__device__ inline float bf2f(unsigned short h) {
    return __uint_as_float(((u32)h) << 16);
}

// ---------------------------------------------------------------------------
// KPREP: fused input prep (Xt bf16 hi/lo padded grid; W' bf16 hi/lo).
// ---------------------------------------------------------------------------
__global__ __launch_bounds__(256) void kprep(const float* __restrict__ feat,
                                             const float* __restrict__ wr,
                                             unsigned short* __restrict__ xthi,
                                             unsigned short* __restrict__ xtlo,
                                             unsigned short* __restrict__ whi,
                                             unsigned short* __restrict__ wlo)
{
    __shared__ float sh[4608];
    int bid = blockIdx.x;
    int t = threadIdx.x;
    if (bid < 416) {
        float (*tile)[65] = (float(*)[65])sh;
        int gr = bid >> 3;          // grid row 0..51
        int cc = bid & 7;           // c-chunk
        int tx = t & 63, ty = t >> 6;
        int y = gr - 1;
        bool rowok = (gr >= 1) && (gr <= 50);
#pragma unroll
        for (int i = 0; i < 16; ++i) {
            int c = i * 4 + ty;
            tile[c][tx] = (rowok && tx < 50)
                        ? feat[(size_t)(cc * 64 + c) * NPX + y * 50 + tx] : 0.f;
        }
        __syncthreads();
#pragma unroll
        for (int i = 0; i < 16; ++i) {
            int xp = i * 4 + ty;
            int cell = gr * 64 + xp;
            bool ok = rowok && xp >= 1 && xp <= 50;
            float v = ok ? tile[tx][xp - 1] : 0.f;
            unsigned short hi = f2bf(v);
            xthi[(size_t)cell * 512 + cc * 64 + tx] = hi;
            xtlo[(size_t)cell * 512 + cc * 64 + tx] = f2bf(v - bf2f(hi));
        }
    } else {
        int oc = bid - 416;         // 0..511
        for (int j = t; j < 4608; j += 256) sh[j] = wr[(size_t)oc * 4608 + j];
        __syncthreads();
        for (int k = t; k < 4608; k += 256) {
            int c = k & 511, tap = k >> 9;
            float v = sh[c * 9 + tap];
            unsigned short hi = f2bf(v);
            whi[(size_t)oc * 4608 + k] = hi;
            wlo[(size_t)oc * 4608 + k] = f2bf(v - bf2f(hi));
        }
    }
}

// ---------------------------------------------------------------------------
// K1m v7: LDS-staged MFMA GEMM, re-tiled for occupancy. R9's 128x128 blocks
// (64KB LDS, 320 blocks) capped at 2 blocks/CU with a 2:1 tail imbalance.
// v7: block = 128oc x 64px, 48KB LDS -> 3 blocks/CU, 640 blocks (1.5 imbal).
// Wave = 64oc x 32px (4x2 16x16 tiles). Same K-order as R9 (absmax 0.5).
// ---------------------------------------------------------------------------
__global__ __launch_bounds__(256) void k1m(const unsigned short* __restrict__ xthi,
                                           const unsigned short* __restrict__ xtlo,
                                           const unsigned short* __restrict__ whi,
                                           const unsigned short* __restrict__ wlo,
                                           float* __restrict__ pk,
                                           int cptLog, int cptm1, int cptMul, int niter)
{
    __shared__ __align__(16) unsigned short Ah[8192];   // 128oc x 64k
    __shared__ __align__(16) unsigned short Al[8192];
    __shared__ __align__(16) unsigned short Bh[4096];   // 64px x 64k
    __shared__ __align__(16) unsigned short Bl[4096];

    int t = threadIdx.x;
    int lane = t & 63, wave = t >> 6;
    int wo = wave & 1, wp = wave >> 1;   // wo: 64-oc half, wp: 32-px half
    int ocb = blockIdx.x, pxb = blockIdx.y, bs = blockIdx.z;
    int q = lane >> 4, m = lane & 15;
    int c0base = bs * cptMul;

    // staging geometry: thread -> granule g (16B) of row r0 (+32i)
    int g  = t & 7;
    int r0 = t >> 3;                     // 0..31
    int ocA[4];
    int cellB[2];
#pragma unroll
    for (int i = 0; i < 4; ++i) ocA[i] = ocb * 128 + r0 + 32 * i;
#pragma unroll
    for (int i = 0; i < 2; ++i) {
        int opx = pxb * 64 + r0 + 32 * i;
        cellB[i] = (opx < NPX) ? ((opx / 50) + 1) * 64 + (opx % 50) + 1 : 190;
    }

    f32x4 acc[8];
    f32x4 zf = {0.f, 0.f, 0.f, 0.f};
#pragma unroll
    for (int i = 0; i < 8; ++i) acc[i] = zf;

    for (int it = 0; it < niter; ++it) {
        int tap = it >> cptLog;
        int cw  = it & cptm1;
        int c0  = c0base + cw * 64;
        int t3  = (tap * 43) >> 7;                      // tap/3
        int tapoff = (t3 - 1) * 64 + (tap - t3 * 3) - 1;
        // ---- stage 48KB ----
#pragma unroll
        for (int i = 0; i < 4; ++i) {
            int rl = r0 + 32 * i;
            int la = rl * 64 + g * 8;
            size_t ga = (size_t)ocA[i] * 4608 + tap * 512 + c0 + g * 8;
            *(bf16x8*)(Ah + la) = *(const bf16x8*)(whi + ga);
            *(bf16x8*)(Al + la) = *(const bf16x8*)(wlo + ga);
        }
#pragma unroll
        for (int i = 0; i < 2; ++i) {
            int rl = r0 + 32 * i;
            int la = rl * 64 + g * 8;
            size_t gb = (size_t)(cellB[i] + tapoff) * 512 + c0 + g * 8;
            *(bf16x8*)(Bh + la) = *(const bf16x8*)(xthi + gb);
            *(bf16x8*)(Bl + la) = *(const bf16x8*)(xtlo + gb);
        }
        __syncthreads();
        // ---- compute: 2 k-steps of 32 ----
#pragma unroll
        for (int ks = 0; ks < 2; ++ks) {
            bf16x8 fah[4], fal[4], fbh[2], fbl[2];
#pragma unroll
            for (int mt = 0; mt < 4; ++mt) {
                int off = (wo * 64 + mt * 16 + m) * 64 + ks * 32 + q * 8;
                fah[mt] = *(const bf16x8*)(Ah + off);
                fal[mt] = *(const bf16x8*)(Al + off);
            }
#pragma unroll
            for (int nt = 0; nt < 2; ++nt) {
                int off = (wp * 32 + nt * 16 + m) * 64 + ks * 32 + q * 8;
                fbh[nt] = *(const bf16x8*)(Bh + off);
                fbl[nt] = *(const bf16x8*)(Bl + off);
            }
#pragma unroll
            for (int mt = 0; mt < 4; ++mt)
#pragma unroll
                for (int nt = 0; nt < 2; ++nt) {
                    f32x4 a = acc[mt * 2 + nt];
                    a = __builtin_amdgcn_mfma_f32_16x16x32_bf16(fal[mt], fbh[nt], a, 0, 0, 0);
                    a = __builtin_amdgcn_mfma_f32_16x16x32_bf16(fah[mt], fbl[nt], a, 0, 0, 0);
                    a = __builtin_amdgcn_mfma_f32_16x16x32_bf16(fah[mt], fbh[nt], a, 0, 0, 0);
                    acc[mt * 2 + nt] = a;
                }
        }
        __syncthreads();
    }
    // C/D: col(px)=lane&15, row(oc)=quad*4+reg
#pragma unroll
    for (int mt = 0; mt < 4; ++mt)
#pragma unroll
        for (int nt = 0; nt < 2; ++nt)
#pragma unroll
            for (int r = 0; r < 4; ++r) {
                int oc = ocb * 128 + wo * 64 + mt * 16 + q * 4 + r;
                int px = pxb * 64 + wp * 32 + nt * 16 + m;
                pk[((size_t)bs * 512 + oc) * 2560 + px] = acc[mt * 2 + nt][r];
            }
}

// ---------------------------------------------------------------------------
// K2a: fused k-split reduce + bias + ReLU + 1x1 heads partial GEMM.
// ---------------------------------------------------------------------------
__global__ __launch_bounds__(256) void k2a_heads(const float* __restrict__ pk, int ns,
                                                 const float* __restrict__ br,
                                                 const float* __restrict__ wcls,
                                                 const float* __restrict__ wreg,
                                                 float* __restrict__ part)
{
    __shared__ float vt[64 * 64];
    __shared__ float Wl[45 * 64];
    int t  = threadIdx.x;
    int pb = blockIdx.x;           // 0..39
    int s  = blockIdx.y;           // 0..7
    int cb = s * 64;
    for (int e = t; e < 45 * 64; e += 256) {
        int u = e >> 6, c = e & 63;
        Wl[e] = (u < 9) ? wcls[u * 512 + cb + c] : wreg[(u - 9) * 512 + cb + c];
    }
    int pxl = t & 63, ug = t >> 6;
    int px = pb * 64 + pxl;
    bool ok = px < NPX;
#pragma unroll
    for (int i = 0; i < 16; ++i) {
        int c = ug * 16 + i;       // wave-uniform
        float v = 0.f;
        if (ok) {
            size_t bidx = (size_t)(cb + c) * 2560 + px;
            v = br[cb + c];
            for (int ks = 0; ks < ns; ++ks) v += pk[(size_t)ks * 512 * 2560 + bidx];
            v = v > 0.f ? v : 0.f;
        }
        vt[c * 64 + pxl] = v;
    }
    __syncthreads();
    int ubase = ug * 12;
    int ulim  = (45 - ubase < 12) ? (45 - ubase) : 12;
    float acc[12];
#pragma unroll
    for (int j = 0; j < 12; ++j) acc[j] = 0.f;
    for (int c = 0; c < 64; ++c) {
        float v = vt[c * 64 + pxl];
#pragma unroll
        for (int j = 0; j < 12; ++j)
            acc[j] = fmaf(v, Wl[(ubase + j) * 64 + c], acc[j]);
    }
    if (ok) {
        for (int j = 0; j < ulim; ++j)
            part[((size_t)s * 45 + ubase + j) * NPX + px] = acc[j];
    }
}

// ---------------------------------------------------------------------------
// K2b: reduce partials + bias, sigmoid, decode, clip, validity, sort key.
// ---------------------------------------------------------------------------
__global__ __launch_bounds__(256) void k2b_decode(const float* __restrict__ part,
                                                  const float* __restrict__ bcls,
                                                  const float* __restrict__ breg,
                                                  AnchorBase ab,
                                                  float* __restrict__ score,
                                                  float* __restrict__ bx1, float* __restrict__ by1,
                                                  float* __restrict__ bx2, float* __restrict__ by2,
                                                  u32* __restrict__ valid,
                                                  u64* __restrict__ key)
{
    int id = blockIdx.x * 256 + threadIdx.x;
    if (id >= NANCH) return;
    int k  = id / NPX;
    int px = id - k * NPX;

    float z  = bcls[k];
    float d0 = breg[k * 4 + 0], d1 = breg[k * 4 + 1];
    float d2 = breg[k * 4 + 2], d3 = breg[k * 4 + 3];
#pragma unroll
    for (int s = 0; s < 8; ++s) {
        const float* p = part + (size_t)s * 45 * NPX;
        z  += p[(size_t)k * NPX + px];
        d0 += p[(size_t)(9 + k * 4 + 0) * NPX + px];
        d1 += p[(size_t)(9 + k * 4 + 1) * NPX + px];
        d2 += p[(size_t)(9 + k * 4 + 2) * NPX + px];
        d3 += p[(size_t)(9 + k * 4 + 3) * NPX + px];
    }
    float sc = 1.f / (1.f + expf(-z));

    int yy = px / 50, xx = px - (px / 50) * 50;
    float fx = (float)xx, fy = (float)yy;
    float ax1 = fx + ab.b[k * 4 + 0], ay1 = fy + ab.b[k * 4 + 1];
    float ax2 = fx + ab.b[k * 4 + 2], ay2 = fy + ab.b[k * 4 + 3];
    float aw = ax2 - ax1, ah = ay2 - ay1;
    float cx = ax1 + 0.5f * aw, cy = ay1 + 0.5f * ah;
    float pcx = d0 * aw + cx, pcy = d1 * ah + cy;
    float pw = expf(d2) * aw, ph = expf(d3) * ah;
    float x1 = pcx - 0.5f * pw, y1 = pcy - 0.5f * ph;
    float x2 = pcx + 0.5f * pw, y2 = pcy + 0.5f * ph;
    x1 = fminf(fmaxf(x1, 0.f), 800.f);
    y1 = fminf(fmaxf(y1, 0.f), 800.f);
    x2 = fminf(fmaxf(x2, 0.f), 800.f);
    y2 = fminf(fmaxf(y2, 0.f), 800.f);
    u32 v = ((x2 - x1) >= 16.f) && ((y2 - y1) >= 16.f);

    int f = px * 9 + k;
    score[f] = sc;
    bx1[f] = x1; by1[f] = y1; bx2[f] = x2; by2[f] = y2;
    valid[f] = v;
    u32 sb = __float_as_uint(sc);
    key[f] = ((u64)(~sb) << 32) | (u32)f;
}

// ---------------------------------------------------------------------------
// K3a v4: partial ranks with block-classified 32-bit fast path (R16).
// key = (~score)<<32 | index, low word == element index. For a (bx,jb) block
// whose whole j-range [jLo,jLo+2250) lies strictly BELOW the i-range
// [bx*1024, bx*1024+1024): tie-break (j<i) always true ->
//   partial = #{hj <= hi} = 2250 - #{hj > hi}     (one u32 cmp per pair)
// Strictly ABOVE: tie-break always false -> partial = #{hj < hi}.
// Only ~30/220 blocks straddle the diagonal -> exact u64 path (unchanged).
// Provably identical ranks; pure instruction-count cut in a VALU-throughput-
// bound all-pairs loop (506M compares).
// ---------------------------------------------------------------------------
__global__ __launch_bounds__(256) void k3a_rank(const u64* __restrict__ key,
                                                u32* __restrict__ rankp)
{
    __shared__ __align__(16) u64 sk[2250];
    int t  = threadIdx.x;
    int jb = blockIdx.y;           // 0..9
    int bx = blockIdx.x;           // 0..21
    int iLo = bx << 10;
    int jLo = jb * 2250;
    int i0 = iLo + t;
    int i1 = i0 + 256, i2 = i0 + 512, i3 = i0 + 768;
    size_t base = (size_t)jb * NANCH;

    bool below = (jLo + 2250 <= iLo);
    bool above = (jLo >= iLo + 1024);
    if (below || above) {
        // ---- FAST: single u32 compare per pair ----
        u32* skh = (u32*)sk;
        for (int e = t; e < 2250; e += 256)
            skh[e] = (u32)(key[jLo + e] >> 32);
        __syncthreads();
        u32 k0 = (i0 < NANCH) ? (u32)(key[i0] >> 32) : 0u;
        u32 k1 = (i1 < NANCH) ? (u32)(key[i1] >> 32) : 0u;
        u32 k2 = (i2 < NANCH) ? (u32)(key[i2] >> 32) : 0u;
        u32 k3 = (i3 < NANCH) ? (u32)(key[i3] >> 32) : 0u;
        u32 c0 = 0, c1 = 0, c2 = 0, c3 = 0;
        const uint2* s2 = (const uint2*)skh;
        if (below) {
#pragma unroll 5
            for (int j = 0; j < 1125; ++j) {
                uint2 v = s2[j];
                c0 += (v.x > k0) ? 1u : 0u;  c0 += (v.y > k0) ? 1u : 0u;
                c1 += (v.x > k1) ? 1u : 0u;  c1 += (v.y > k1) ? 1u : 0u;
                c2 += (v.x > k2) ? 1u : 0u;  c2 += (v.y > k2) ? 1u : 0u;
                c3 += (v.x > k3) ? 1u : 0u;  c3 += (v.y > k3) ? 1u : 0u;
            }
            c0 = 2250u - c0; c1 = 2250u - c1; c2 = 2250u - c2; c3 = 2250u - c3;
        } else {
#pragma unroll 5
            for (int j = 0; j < 1125; ++j) {
                uint2 v = s2[j];
                c0 += (v.x < k0) ? 1u : 0u;  c0 += (v.y < k0) ? 1u : 0u;
                c1 += (v.x < k1) ? 1u : 0u;  c1 += (v.y < k1) ? 1u : 0u;
                c2 += (v.x < k2) ? 1u : 0u;  c2 += (v.y < k2) ? 1u : 0u;
                c3 += (v.x < k3) ? 1u : 0u;  c3 += (v.y < k3) ? 1u : 0u;
            }
        }
        if (i0 < NANCH) rankp[base + i0] = c0;
        if (i1 < NANCH) rankp[base + i1] = c1;
        if (i2 < NANCH) rankp[base + i2] = c2;
        if (i3 < NANCH) rankp[base + i3] = c3;
        return;
    }

    // ---- MIXED (straddles diagonal): exact u64 path (original) ----
    for (int e = t; e < 2250; e += 256) sk[e] = key[jLo + e];
    __syncthreads();
    u64 k0 = (i0 < NANCH) ? key[i0] : 0ull;
    u64 k1 = (i1 < NANCH) ? key[i1] : 0ull;
    u64 k2 = (i2 < NANCH) ? key[i2] : 0ull;
    u64 k3 = (i3 < NANCH) ? key[i3] : 0ull;
    u32 c0 = 0, c1 = 0, c2 = 0, c3 = 0;
    const ulonglong2* sk2 = (const ulonglong2*)sk;
#pragma unroll 5
    for (int j = 0; j < 1125; ++j) {
        ulonglong2 v = sk2[j];
        c0 += (v.x < k0) ? 1u : 0u;  c0 += (v.y < k0) ? 1u : 0u;
        c1 += (v.x < k1) ? 1u : 0u;  c1 += (v.y < k1) ? 1u : 0u;
        c2 += (v.x < k2) ? 1u : 0u;  c2 += (v.y < k2) ? 1u : 0u;
        c3 += (v.x < k3) ? 1u : 0u;  c3 += (v.y < k3) ? 1u : 0u;
    }
    if (i0 < NANCH) rankp[base + i0] = c0;
    if (i1 < NANCH) rankp[base + i1] = c1;
    if (i2 < NANCH) rankp[base + i2] = c2;
    if (i3 < NANCH) rankp[base + i3] = c3;
}

// ---------------------------------------------------------------------------
// K3b: sum 10 partial ranks, scatter top-10000 (+ packed float4 boxes);
// sInv[r] = 1 if invalid box.
// ---------------------------------------------------------------------------
__global__ __launch_bounds__(256) void k3b_gather(const u32* __restrict__ rankp,
                                                  const float* __restrict__ score,
                                                  const float* __restrict__ bx1, const float* __restrict__ by1,
                                                  const float* __restrict__ bx2, const float* __restrict__ by2,
                                                  const u32* __restrict__ valid,
                                                  float* __restrict__ sS,
                                                  float* __restrict__ sx1, float* __restrict__ sy1,
                                                  float* __restrict__ sx2, float* __restrict__ sy2,
                                                  float4* __restrict__ sbox4,
                                                  u32* __restrict__ sInv)
{
    int i = blockIdx.x * 256 + threadIdx.x;
    if (i >= NANCH) return;
    u32 r = 0;
#pragma unroll
    for (int c = 0; c < 10; ++c) r += rankp[(size_t)c * NANCH + i];
    if (r >= PRE_TOPK) return;
    float x1 = bx1[i], y1 = by1[i], x2 = bx2[i], y2 = by2[i];
    sS[r] = score[i];
    sx1[r] = x1; sy1[r] = y1; sx2[r] = x2; sy2[r] = y2;
    float4 b4; b4.x = x1; b4.y = y1; b4.z = x2; b4.w = y2;
    sbox4[r] = b4;
    sInv[r] = valid[i] ? 0u : 1u;
}

// ---------------------------------------------------------------------------
// K4 v4: row-per-wave suppression matrix (R10 — verified, ~20us).
// ---------------------------------------------------------------------------
__global__ __launch_bounds__(256) void k4_mat(const float4* __restrict__ sbox4,
                                              u64* __restrict__ rows,
                                              u64* __restrict__ selfw)
{
    int t = threadIdx.x, lane = t & 63, wave = t >> 6;
    int i = blockIdx.x * 4 + wave;
    if (i >= PRE_TOPK) return;
    float4 bi = sbox4[i];                       // wave-uniform, loaded once
    float ai = (bi.z - bi.x) * (bi.w - bi.y);
    int wd  = i >> 6;
    int ish = i & 63;
    u64 diagmask = ~((2ull << ish) - 1ull);     // ish=63 -> 0 (no j>i in word)
    u64* rowp = rows + (size_t)i * NWORDS;
    for (int w = wd; w < 157; ++w) {
        float4 bj = sbox4[(w << 6) + lane];     // coalesced dwordx4
        float xx1 = fmaxf(bi.x, bj.x);
        float yy1 = fmaxf(bi.y, bj.y);
        float xx2 = fminf(bi.z, bj.z);
        float yy2 = fminf(bi.w, bj.w);
        float iw = fmaxf(xx2 - xx1, 0.f);
        float ih = fmaxf(yy2 - yy1, 0.f);
        float inter = iw * ih;
        float aj = (bj.z - bj.x) * (bj.w - bj.y);
        float uni = ai + aj - inter;
        u64 b = __ballot(inter > 0.7f * uni);
        if (w == wd)  b &= diagmask;
        if (w == 156) b &= 0xFFFFull;
        if (lane == 0) {
            rowp[w] = b;
            if (w == wd) selfw[i] = b;
        }
    }
}

// ---------------------------------------------------------------------------
// K5 v6 (R3-verified 65.4us — FINAL): word-scan + scalar readlane resolve +
// batch-16 commit. R14/R15/R16 post-mortems: group-resolve (v7, 88.9us) and
// dead-slot conditional loads (v8, 81.1us) both regressed — the commit's
// unconditional back-to-back load clustering IS the optimum; k5 is
// latency-wait-bound at this structure. Do not touch.
// ---------------------------------------------------------------------------
__global__ __launch_bounds__(64) void k5_scan(const u64* __restrict__ rows,
                                              const u64* __restrict__ selfw,
                                              const u32* __restrict__ sInv,
                                              const float* __restrict__ sS,
                                              const float* __restrict__ sx1, const float* __restrict__ sy1,
                                              const float* __restrict__ sx2, const float* __restrict__ sy2,
                                              float* __restrict__ out)
{
    __shared__ int keptList[2000];
    __shared__ int kcnt;
    int l = threadIdx.x;
    auto bw = [&](int w) -> u64 {
        const uint4* p = (const uint4*)(sInv + (size_t)w * 64);
        u64 v = 0;
#pragma unroll
        for (int j = 0; j < 16; ++j) {
            uint4 q = p[j];
            v |= ((u64)(q.x != 0) << (j * 4))     | ((u64)(q.y != 0) << (j * 4 + 1))
               | ((u64)(q.z != 0) << (j * 4 + 2)) | ((u64)(q.w != 0) << (j * 4 + 3));
        }
        return v;
    };
    // 64-bit uniform readlane helper (2x v_readlane_b32)
    auto rdlane64 = [&](u64 v, int src) -> u64 {
        u32 lo = __builtin_amdgcn_readlane((u32)v, src);
        u32 hi = __builtin_amdgcn_readlane((u32)(v >> 32), src);
        return ((u64)hi << 32) | lo;
    };
    u64 r0 = bw(l);
    u64 r1 = bw(64 + l);
    u64 r2 = (l < 32) ? bw(128 + l) : ~0ull;

    // depth-8 selfw prefetch ring in named registers (static, no array)
    u64 s0 = selfw[(size_t)0 * 64 + l];
    u64 s1 = selfw[(size_t)1 * 64 + l];
    u64 s2 = selfw[(size_t)2 * 64 + l];
    u64 s3 = selfw[(size_t)3 * 64 + l];
    u64 s4 = selfw[(size_t)4 * 64 + l];
    u64 s5 = selfw[(size_t)5 * 64 + l];
    u64 s6 = selfw[(size_t)6 * 64 + l];
    u64 s7 = selfw[(size_t)7 * 64 + l];

    int cnt = 0;
    bool done = false;
    for (int w = 0; w < 157; ++w) {
        u64 swreg = s0;
        s0 = s1; s1 = s2; s2 = s3; s3 = s4; s4 = s5; s5 = s6; s6 = s7;
        s7 = (w + 8 < 157) ? selfw[(size_t)(w + 8) * 64 + l] : 0ull;

        int slot = w >> 6, owner = w & 63;
        u64 val = (slot == 0) ? r0 : (slot == 1) ? r1 : r2;
        u64 rw = rdlane64(val, owner);
        u64 wmask = (w == 156) ? 0xFFFFull : ~0ull;
        u64 av = (~rw) & wmask;

        // ---- intra-word greedy resolve: scalar chain via readlane ----
        u64 km = 0;
        while (av) {
            int b = __builtin_ctzll(av);
            u64 sw = rdlane64(swreg, b);
            km |= 1ull << b;
            av &= ~(1ull << b);
            av &= ~sw;
        }
        // ---- commit: OR kept rows in batches of 16 (loads back-to-back) ----
        u64 kk = km;
        while (kk) {
            int bsx[16];
            int nb = 0;
            while (kk && nb < 16) {
                int b = __builtin_ctzll(kk);
                kk &= kk - 1;
                bsx[nb++] = b;
            }
            u64 a0 = 0, a1 = 0, a2 = 0;
#pragma unroll
            for (int u = 0; u < 16; ++u) {
                if (u < nb) {
                    int i = (w << 6) + bsx[u];
                    if (l == 0 && cnt + u < 2000) keptList[cnt + u] = i;
                    const u64* rp = rows + (size_t)i * NWORDS;
                    a0 |= rp[l];
                    a1 |= rp[64 + l];
                    if (l < 32) a2 |= rp[128 + l];
                }
            }
            r0 |= a0; r1 |= a1; r2 |= a2;
            cnt += nb;
            if (cnt >= 2000) { done = true; break; }
        }
        if (done) break;
    }
    if (l == 0) kcnt = (cnt < 2000) ? cnt : 2000;
    __syncthreads();
    int K = kcnt;
    for (int r = l; r < 2000; r += 64) {
        if (r < K) {
            int j = keptList[r];
            out[r * 4 + 0] = sx1[j];
            out[r * 4 + 1] = sy1[j];
            out[r * 4 + 2] = sx2[j];
            out[r * 4 + 3] = sy2[j];
            out[8000 + r]  = sS[j];
        } else {
            out[r * 4 + 0] = 0.f; out[r * 4 + 1] = 0.f;
            out[r * 4 + 2] = 0.f; out[r * 4 + 3] = 0.f;
            out[8000 + r]  = 0.f;
        }
    }
}

// ---------------------------------------------------------------------------
extern "C" void kernel_launch(void* const* d_in, const int* in_sizes, int n_in,
                              void* d_out, int out_size, void* d_ws, size_t ws_size,
                              hipStream_t stream)
{
    (void)in_sizes; (void)n_in; (void)out_size;
    const float* feat = (const float*)d_in[1];
    const float* wrpn = (const float*)d_in[3];
    const float* brpn = (const float*)d_in[4];
    const float* wcls = (const float*)d_in[5];
    const float* bcls = (const float*)d_in[6];
    const float* wreg = (const float*)d_in[7];
    const float* breg = (const float*)d_in[8];
    float* out = (float*)d_out;

    // K-split factor by workspace budget. need(ns) = ns*512*2560*4 + 16,252,928.
    int ns = (ws_size >= 58195968) ? 8 : (ws_size >= 37224448) ? 4 : 2;
    int cpt     = 8 / ns;                 // 64c-chunks per tap per z-slice
    int cptLog  = (ns == 2) ? 2 : (ns == 4) ? 1 : 0;
    int cptm1   = cpt - 1;
    int cptMul  = cpt * 64;               // c0base = bs * cptMul
    int niter   = 9 * cpt;
    size_t pkB = (size_t)ns * 512 * 2560 * 4;

    char* ws = (char*)d_ws;
    // Live ranges:
    //   [0,pkB)            pk     k1m..k2a
    //   [pkB,pkB+16.25M)   Xt+W   kprep..k1m; then smalls (k2a+), part
    //                      (k2a..k2b) and rows (memset/k4..k5) share offsets.
    float* pk = (float*)ws;
    unsigned short* Xthi = (unsigned short*)(ws + pkB);
    unsigned short* Xtlo = Xthi + (size_t)52 * 64 * 512;
    unsigned short* Whi  = (unsigned short*)(ws + pkB + 6815744);
    unsigned short* Wlo  = Whi + (size_t)512 * 4608;

    char* sm = ws + pkB;
    float* score = (float*)(sm + 0);             // 90,000
    float* bx1   = (float*)(sm + 90000);
    float* by1   = (float*)(sm + 180000);
    float* bx2   = (float*)(sm + 270000);
    float* by2   = (float*)(sm + 360000);
    u32*   valid = (u32*)  (sm + 450000);        // 90,000
    u64*   key   = (u64*)  (sm + 540000);        // 180,000
    u32*   rankp = (u32*)  (sm + 720000);        // 900,000 (10 chunks)
    float* sS    = (float*)(sm + 1620000);       // 40,000
    float* sx1   = (float*)(sm + 1660000);
    float* sy1   = (float*)(sm + 1700000);
    float* sx2   = (float*)(sm + 1740000);
    float* sy2   = (float*)(sm + 1780000);
    u32*   sInv  = (u32*)  (sm + 1820000);       // 40,960
    u64*   selfw = (u64*)  (sm + 1860960);       // 81,920
    float4* sbox4= (float4*)(sm + 1942880);      // 163,840 (10240 entries)
    float* part  = (float*)(sm + 2106720);       // 3,600,000 (k2a..k2b)
    u64*   rows  = (u64*)  (sm + 2106720);       // 12,800,000 (k4..k5) -> ends sm+14.91M < 16.25M
    // peak footprint = pkB + 16,252,928 (ns=4 -> 37.2 MB, proven available)

    AnchorBase ab;
    {
        const float scales[3] = {128.f, 256.f, 512.f};
        const float aspect[3] = {0.5f, 1.f, 2.f};
        for (int ai = 0; ai < 3; ++ai) {
            float hr = sqrtf(aspect[ai]);
            float wratio = 1.0f / hr;
            for (int si = 0; si < 3; ++si) {
                float wsz = wratio * scales[si];
                float hsz = hr * scales[si];
                int a = ai * 3 + si;
                ab.b[a * 4 + 0] = rintf(-wsz / 2.0f);
                ab.b[a * 4 + 1] = rintf(-hsz / 2.0f);
                ab.b[a * 4 + 2] = rintf( wsz / 2.0f);
                ab.b[a * 4 + 3] = rintf( hsz / 2.0f);
            }
        }
    }

    kprep    <<<928, 256, 0, stream>>>(feat, wrpn, Xthi, Xtlo, Whi, Wlo);
    k1m      <<<dim3(4, 40, ns), 256, 0, stream>>>(Xthi, Xtlo, Whi, Wlo, pk,
                                                   cptLog, cptm1, cptMul, niter);
    k2a_heads<<<dim3(40, 8), 256, 0, stream>>>(pk, ns, brpn, wcls, wreg, part);
    k2b_decode<<<88, 256, 0, stream>>>(part, bcls, breg, ab, score, bx1, by1, bx2, by2, valid, key);
    k3a_rank <<<dim3(22, 10), 256, 0, stream>>>(key, rankp);
    k3b_gather<<<88, 256, 0, stream>>>(rankp, score, bx1, by1, bx2, by2, valid,
                                       sS, sx1, sy1, sx2, sy2, sbox4, sInv);
    hipMemsetAsync(rows, 0, (size_t)PRE_TOPK * NWORDS * 8, stream);   // sub-diagonal + tail words
    k4_mat   <<<2500, 256, 0, stream>>>(sbox4, rows, selfw);
    k5_scan  <<<1, 64, 0, stream>>>(rows, selfw, sInv, sS, sx1, sy1, sx2, sy2, out);
}

// Round 7
// 345.491 us; speedup vs baseline: 1.1287x; 1.1287x over previous
//
#include <hip/hip_runtime.h>
#include <cmath>
#include <cstdint>
#include <cstddef>

typedef unsigned long long u64;
typedef unsigned int u32;

#define NPX   2500
#define NANCH 22500
#define PRE_TOPK 10000
#define NWORDS 160      // 160*64 = 10240 bits per NMS row
#define NJC 45          // k3a j-chunks (500 keys each)

struct AnchorBase { float b[36]; };

typedef __attribute__((ext_vector_type(8))) short bf16x8;
typedef __attribute__((ext_vector_type(4))) float f32x4;

__device__ inline unsigned short f2bf(float f) {
    u32 u = __float_as_uint(f);
    u32 r = u + 0x7fffu + ((u >> 16) & 1u);
    return (unsigned short)(r >> 16);
}
__device__ inline float bf2f(unsigned short h) {
    return __uint_as_float(((u32)h) << 16);
}

// ---------------------------------------------------------------------------
// KPREP: fused input prep (Xt bf16 hi/lo padded grid; W' bf16 hi/lo).
// ---------------------------------------------------------------------------
__global__ __launch_bounds__(256) void kprep(const float* __restrict__ feat,
                                             const float* __restrict__ wr,
                                             unsigned short* __restrict__ xthi,
                                             unsigned short* __restrict__ xtlo,
                                             unsigned short* __restrict__ whi,
                                             unsigned short* __restrict__ wlo)
{
    __shared__ float sh[4608];
    int bid = blockIdx.x;
    int t = threadIdx.x;
    if (bid < 416) {
        float (*tile)[65] = (float(*)[65])sh;
        int gr = bid >> 3;          // grid row 0..51
        int cc = bid & 7;           // c-chunk
        int tx = t & 63, ty = t >> 6;
        int y = gr - 1;
        bool rowok = (gr >= 1) && (gr <= 50);
#pragma unroll
        for (int i = 0; i < 16; ++i) {
            int c = i * 4 + ty;
            tile[c][tx] = (rowok && tx < 50)
                        ? feat[(size_t)(cc * 64 + c) * NPX + y * 50 + tx] : 0.f;
        }
        __syncthreads();
#pragma unroll
        for (int i = 0; i < 16; ++i) {
            int xp = i * 4 + ty;
            int cell = gr * 64 + xp;
            bool ok = rowok && xp >= 1 && xp <= 50;
            float v = ok ? tile[tx][xp - 1] : 0.f;
            unsigned short hi = f2bf(v);
            xthi[(size_t)cell * 512 + cc * 64 + tx] = hi;
            xtlo[(size_t)cell * 512 + cc * 64 + tx] = f2bf(v - bf2f(hi));
        }
    } else {
        int oc = bid - 416;         // 0..511
        for (int j = t; j < 4608; j += 256) sh[j] = wr[(size_t)oc * 4608 + j];
        __syncthreads();
        for (int k = t; k < 4608; k += 256) {
            int c = k & 511, tap = k >> 9;
            float v = sh[c * 9 + tap];
            unsigned short hi = f2bf(v);
            whi[(size_t)oc * 4608 + k] = hi;
            wlo[(size_t)oc * 4608 + k] = f2bf(v - bf2f(hi));
        }
    }
}

// ---------------------------------------------------------------------------
// K1m v7: LDS-staged MFMA GEMM, re-tiled for occupancy. R9's 128x128 blocks
// (64KB LDS, 320 blocks) capped at 2 blocks/CU with a 2:1 tail imbalance.
// v7: block = 128oc x 64px, 48KB LDS -> 3 blocks/CU, 640 blocks (1.5 imbal).
// Wave = 64oc x 32px (4x2 16x16 tiles). Same K-order as R9 (absmax 0.5).
// ---------------------------------------------------------------------------
__global__ __launch_bounds__(256) void k1m(const unsigned short* __restrict__ xthi,
                                           const unsigned short* __restrict__ xtlo,
                                           const unsigned short* __restrict__ whi,
                                           const unsigned short* __restrict__ wlo,
                                           float* __restrict__ pk,
                                           int cptLog, int cptm1, int cptMul, int niter)
{
    __shared__ __align__(16) unsigned short Ah[8192];   // 128oc x 64k
    __shared__ __align__(16) unsigned short Al[8192];
    __shared__ __align__(16) unsigned short Bh[4096];   // 64px x 64k
    __shared__ __align__(16) unsigned short Bl[4096];

    int t = threadIdx.x;
    int lane = t & 63, wave = t >> 6;
    int wo = wave & 1, wp = wave >> 1;   // wo: 64-oc half, wp: 32-px half
    int ocb = blockIdx.x, pxb = blockIdx.y, bs = blockIdx.z;
    int q = lane >> 4, m = lane & 15;
    int c0base = bs * cptMul;

    // staging geometry: thread -> granule g (16B) of row r0 (+32i)
    int g  = t & 7;
    int r0 = t >> 3;                     // 0..31
    int ocA[4];
    int cellB[2];
#pragma unroll
    for (int i = 0; i < 4; ++i) ocA[i] = ocb * 128 + r0 + 32 * i;
#pragma unroll
    for (int i = 0; i < 2; ++i) {
        int opx = pxb * 64 + r0 + 32 * i;
        cellB[i] = (opx < NPX) ? ((opx / 50) + 1) * 64 + (opx % 50) + 1 : 190;
    }

    f32x4 acc[8];
    f32x4 zf = {0.f, 0.f, 0.f, 0.f};
#pragma unroll
    for (int i = 0; i < 8; ++i) acc[i] = zf;

    for (int it = 0; it < niter; ++it) {
        int tap = it >> cptLog;
        int cw  = it & cptm1;
        int c0  = c0base + cw * 64;
        int t3  = (tap * 43) >> 7;                      // tap/3
        int tapoff = (t3 - 1) * 64 + (tap - t3 * 3) - 1;
        // ---- stage 48KB ----
#pragma unroll
        for (int i = 0; i < 4; ++i) {
            int rl = r0 + 32 * i;
            int la = rl * 64 + g * 8;
            size_t ga = (size_t)ocA[i] * 4608 + tap * 512 + c0 + g * 8;
            *(bf16x8*)(Ah + la) = *(const bf16x8*)(whi + ga);
            *(bf16x8*)(Al + la) = *(const bf16x8*)(wlo + ga);
        }
#pragma unroll
        for (int i = 0; i < 2; ++i) {
            int rl = r0 + 32 * i;
            int la = rl * 64 + g * 8;
            size_t gb = (size_t)(cellB[i] + tapoff) * 512 + c0 + g * 8;
            *(bf16x8*)(Bh + la) = *(const bf16x8*)(xthi + gb);
            *(bf16x8*)(Bl + la) = *(const bf16x8*)(xtlo + gb);
        }
        __syncthreads();
        // ---- compute: 2 k-steps of 32 ----
#pragma unroll
        for (int ks = 0; ks < 2; ++ks) {
            bf16x8 fah[4], fal[4], fbh[2], fbl[2];
#pragma unroll
            for (int mt = 0; mt < 4; ++mt) {
                int off = (wo * 64 + mt * 16 + m) * 64 + ks * 32 + q * 8;
                fah[mt] = *(const bf16x8*)(Ah + off);
                fal[mt] = *(const bf16x8*)(Al + off);
            }
#pragma unroll
            for (int nt = 0; nt < 2; ++nt) {
                int off = (wp * 32 + nt * 16 + m) * 64 + ks * 32 + q * 8;
                fbh[nt] = *(const bf16x8*)(Bh + off);
                fbl[nt] = *(const bf16x8*)(Bl + off);
            }
#pragma unroll
            for (int mt = 0; mt < 4; ++mt)
#pragma unroll
                for (int nt = 0; nt < 2; ++nt) {
                    f32x4 a = acc[mt * 2 + nt];
                    a = __builtin_amdgcn_mfma_f32_16x16x32_bf16(fal[mt], fbh[nt], a, 0, 0, 0);
                    a = __builtin_amdgcn_mfma_f32_16x16x32_bf16(fah[mt], fbl[nt], a, 0, 0, 0);
                    a = __builtin_amdgcn_mfma_f32_16x16x32_bf16(fah[mt], fbh[nt], a, 0, 0, 0);
                    acc[mt * 2 + nt] = a;
                }
        }
        __syncthreads();
    }
    // C/D: col(px)=lane&15, row(oc)=quad*4+reg
#pragma unroll
    for (int mt = 0; mt < 4; ++mt)
#pragma unroll
        for (int nt = 0; nt < 2; ++nt)
#pragma unroll
            for (int r = 0; r < 4; ++r) {
                int oc = ocb * 128 + wo * 64 + mt * 16 + q * 4 + r;
                int px = pxb * 64 + wp * 32 + nt * 16 + m;
                pk[((size_t)bs * 512 + oc) * 2560 + px] = acc[mt * 2 + nt][r];
            }
}

// ---------------------------------------------------------------------------
// K2a: fused k-split reduce + bias + ReLU + 1x1 heads partial GEMM.
// ---------------------------------------------------------------------------
__global__ __launch_bounds__(256) void k2a_heads(const float* __restrict__ pk, int ns,
                                                 const float* __restrict__ br,
                                                 const float* __restrict__ wcls,
                                                 const float* __restrict__ wreg,
                                                 float* __restrict__ part)
{
    __shared__ float vt[64 * 64];
    __shared__ float Wl[45 * 64];
    int t  = threadIdx.x;
    int pb = blockIdx.x;           // 0..39
    int s  = blockIdx.y;           // 0..7
    int cb = s * 64;
    for (int e = t; e < 45 * 64; e += 256) {
        int u = e >> 6, c = e & 63;
        Wl[e] = (u < 9) ? wcls[u * 512 + cb + c] : wreg[(u - 9) * 512 + cb + c];
    }
    int pxl = t & 63, ug = t >> 6;
    int px = pb * 64 + pxl;
    bool ok = px < NPX;
#pragma unroll
    for (int i = 0; i < 16; ++i) {
        int c = ug * 16 + i;       // wave-uniform
        float v = 0.f;
        if (ok) {
            size_t bidx = (size_t)(cb + c) * 2560 + px;
            v = br[cb + c];
            for (int ks = 0; ks < ns; ++ks) v += pk[(size_t)ks * 512 * 2560 + bidx];
            v = v > 0.f ? v : 0.f;
        }
        vt[c * 64 + pxl] = v;
    }
    __syncthreads();
    int ubase = ug * 12;
    int ulim  = (45 - ubase < 12) ? (45 - ubase) : 12;
    float acc[12];
#pragma unroll
    for (int j = 0; j < 12; ++j) acc[j] = 0.f;
    for (int c = 0; c < 64; ++c) {
        float v = vt[c * 64 + pxl];
#pragma unroll
        for (int j = 0; j < 12; ++j)
            acc[j] = fmaf(v, Wl[(ubase + j) * 64 + c], acc[j]);
    }
    if (ok) {
        for (int j = 0; j < ulim; ++j)
            part[((size_t)s * 45 + ubase + j) * NPX + px] = acc[j];
    }
}

// ---------------------------------------------------------------------------
// K2b: reduce partials + bias, sigmoid, decode, clip, validity, sort key.
// ---------------------------------------------------------------------------
__global__ __launch_bounds__(256) void k2b_decode(const float* __restrict__ part,
                                                  const float* __restrict__ bcls,
                                                  const float* __restrict__ breg,
                                                  AnchorBase ab,
                                                  float* __restrict__ score,
                                                  float* __restrict__ bx1, float* __restrict__ by1,
                                                  float* __restrict__ bx2, float* __restrict__ by2,
                                                  u32* __restrict__ valid,
                                                  u64* __restrict__ key)
{
    int id = blockIdx.x * 256 + threadIdx.x;
    if (id >= NANCH) return;
    int k  = id / NPX;
    int px = id - k * NPX;

    float z  = bcls[k];
    float d0 = breg[k * 4 + 0], d1 = breg[k * 4 + 1];
    float d2 = breg[k * 4 + 2], d3 = breg[k * 4 + 3];
#pragma unroll
    for (int s = 0; s < 8; ++s) {
        const float* p = part + (size_t)s * 45 * NPX;
        z  += p[(size_t)k * NPX + px];
        d0 += p[(size_t)(9 + k * 4 + 0) * NPX + px];
        d1 += p[(size_t)(9 + k * 4 + 1) * NPX + px];
        d2 += p[(size_t)(9 + k * 4 + 2) * NPX + px];
        d3 += p[(size_t)(9 + k * 4 + 3) * NPX + px];
    }
    float sc = 1.f / (1.f + expf(-z));

    int yy = px / 50, xx = px - (px / 50) * 50;
    float fx = (float)xx, fy = (float)yy;
    float ax1 = fx + ab.b[k * 4 + 0], ay1 = fy + ab.b[k * 4 + 1];
    float ax2 = fx + ab.b[k * 4 + 2], ay2 = fy + ab.b[k * 4 + 3];
    float aw = ax2 - ax1, ah = ay2 - ay1;
    float cx = ax1 + 0.5f * aw, cy = ay1 + 0.5f * ah;
    float pcx = d0 * aw + cx, pcy = d1 * ah + cy;
    float pw = expf(d2) * aw, ph = expf(d3) * ah;
    float x1 = pcx - 0.5f * pw, y1 = pcy - 0.5f * ph;
    float x2 = pcx + 0.5f * pw, y2 = pcy + 0.5f * ph;
    x1 = fminf(fmaxf(x1, 0.f), 800.f);
    y1 = fminf(fmaxf(y1, 0.f), 800.f);
    x2 = fminf(fmaxf(x2, 0.f), 800.f);
    y2 = fminf(fmaxf(y2, 0.f), 800.f);
    u32 v = ((x2 - x1) >= 16.f) && ((y2 - y1) >= 16.f);

    int f = px * 9 + k;
    score[f] = sc;
    bx1[f] = x1; by1[f] = y1; bx2[f] = x2; by2[f] = y2;
    valid[f] = v;
    u32 sb = __float_as_uint(sc);
    key[f] = ((u64)(~sb) << 32) | (u32)f;
}

// ---------------------------------------------------------------------------
// K3a v5: u64 all-pairs partial ranks (R10-verified core), re-gridded for
// occupancy. R17 diagnosis: 22x10 grid = 220 blocks on 256 CUs -> 8.6%
// occupancy, VALUBusy 29% -> latency-bound at ~1 wave/SIMD, ~4x off the
// ~13us VALU roofline. (R16's u32 fast path attacked instruction count --
// wrong regime -- and regressed; reverted.) v5: j-chunks 10 -> 45 (500 keys,
// 4KB LDS), grid 22x45 = 990 blocks ~ 15 waves/CU. Inner loop byte-identical
// 4-way i-blocked u64 compare, 250 ulonglong2 iterations.
// ---------------------------------------------------------------------------
__global__ __launch_bounds__(256) void k3a_rank(const u64* __restrict__ key,
                                                u32* __restrict__ rankp)
{
    __shared__ __align__(16) u64 sk[500];
    int t  = threadIdx.x;
    int jb = blockIdx.y;           // 0..44
    int jLo = jb * 500;
    for (int e = t; e < 500; e += 256) sk[e] = key[jLo + e];
    __syncthreads();
    int i0 = blockIdx.x * 1024 + t;
    int i1 = i0 + 256, i2 = i0 + 512, i3 = i0 + 768;
    u64 k0 = (i0 < NANCH) ? key[i0] : 0ull;
    u64 k1 = (i1 < NANCH) ? key[i1] : 0ull;
    u64 k2 = (i2 < NANCH) ? key[i2] : 0ull;
    u64 k3 = (i3 < NANCH) ? key[i3] : 0ull;
    u32 c0 = 0, c1 = 0, c2 = 0, c3 = 0;
    const ulonglong2* sk2 = (const ulonglong2*)sk;
#pragma unroll 5
    for (int j = 0; j < 250; ++j) {
        ulonglong2 v = sk2[j];
        c0 += (v.x < k0) ? 1u : 0u;  c0 += (v.y < k0) ? 1u : 0u;
        c1 += (v.x < k1) ? 1u : 0u;  c1 += (v.y < k1) ? 1u : 0u;
        c2 += (v.x < k2) ? 1u : 0u;  c2 += (v.y < k2) ? 1u : 0u;
        c3 += (v.x < k3) ? 1u : 0u;  c3 += (v.y < k3) ? 1u : 0u;
    }
    size_t base = (size_t)jb * NANCH;
    if (i0 < NANCH) rankp[base + i0] = c0;
    if (i1 < NANCH) rankp[base + i1] = c1;
    if (i2 < NANCH) rankp[base + i2] = c2;
    if (i3 < NANCH) rankp[base + i3] = c3;
}

// ---------------------------------------------------------------------------
// K3b: sum 45 partial ranks, scatter top-10000 (+ packed float4 boxes);
// sInv[r] = 1 if invalid box.
// ---------------------------------------------------------------------------
__global__ __launch_bounds__(256) void k3b_gather(const u32* __restrict__ rankp,
                                                  const float* __restrict__ score,
                                                  const float* __restrict__ bx1, const float* __restrict__ by1,
                                                  const float* __restrict__ bx2, const float* __restrict__ by2,
                                                  const u32* __restrict__ valid,
                                                  float* __restrict__ sS,
                                                  float* __restrict__ sx1, float* __restrict__ sy1,
                                                  float* __restrict__ sx2, float* __restrict__ sy2,
                                                  float4* __restrict__ sbox4,
                                                  u32* __restrict__ sInv)
{
    int i = blockIdx.x * 256 + threadIdx.x;
    if (i >= NANCH) return;
    u32 r = 0;
#pragma unroll
    for (int c = 0; c < NJC; ++c) r += rankp[(size_t)c * NANCH + i];
    if (r >= PRE_TOPK) return;
    float x1 = bx1[i], y1 = by1[i], x2 = bx2[i], y2 = by2[i];
    sS[r] = score[i];
    sx1[r] = x1; sy1[r] = y1; sx2[r] = x2; sy2[r] = y2;
    float4 b4; b4.x = x1; b4.y = y1; b4.z = x2; b4.w = y2;
    sbox4[r] = b4;
    sInv[r] = valid[i] ? 0u : 1u;
}

// ---------------------------------------------------------------------------
// K4 v4: row-per-wave suppression matrix (R10 — verified, ~20us).
// ---------------------------------------------------------------------------
__global__ __launch_bounds__(256) void k4_mat(const float4* __restrict__ sbox4,
                                              u64* __restrict__ rows,
                                              u64* __restrict__ selfw)
{
    int t = threadIdx.x, lane = t & 63, wave = t >> 6;
    int i = blockIdx.x * 4 + wave;
    if (i >= PRE_TOPK) return;
    float4 bi = sbox4[i];                       // wave-uniform, loaded once
    float ai = (bi.z - bi.x) * (bi.w - bi.y);
    int wd  = i >> 6;
    int ish = i & 63;
    u64 diagmask = ~((2ull << ish) - 1ull);     // ish=63 -> 0 (no j>i in word)
    u64* rowp = rows + (size_t)i * NWORDS;
    for (int w = wd; w < 157; ++w) {
        float4 bj = sbox4[(w << 6) + lane];     // coalesced dwordx4
        float xx1 = fmaxf(bi.x, bj.x);
        float yy1 = fmaxf(bi.y, bj.y);
        float xx2 = fminf(bi.z, bj.z);
        float yy2 = fminf(bi.w, bj.w);
        float iw = fmaxf(xx2 - xx1, 0.f);
        float ih = fmaxf(yy2 - yy1, 0.f);
        float inter = iw * ih;
        float aj = (bj.z - bj.x) * (bj.w - bj.y);
        float uni = ai + aj - inter;
        u64 b = __ballot(inter > 0.7f * uni);
        if (w == wd)  b &= diagmask;
        if (w == 156) b &= 0xFFFFull;
        if (lane == 0) {
            rowp[w] = b;
            if (w == wd) selfw[i] = b;
        }
    }
}

// ---------------------------------------------------------------------------
// K5 v6 (R3-verified 65.4us — FINAL): word-scan + scalar readlane resolve +
// batch-16 commit. R14/R15/R16 post-mortems: group-resolve (v7, 88.9us) and
// dead-slot conditional loads (v8, 81.1us) both regressed — the commit's
// unconditional back-to-back load clustering IS the optimum; k5 is
// latency-wait-bound at this structure. Do not touch.
// ---------------------------------------------------------------------------
__global__ __launch_bounds__(64) void k5_scan(const u64* __restrict__ rows,
                                              const u64* __restrict__ selfw,
                                              const u32* __restrict__ sInv,
                                              const float* __restrict__ sS,
                                              const float* __restrict__ sx1, const float* __restrict__ sy1,
                                              const float* __restrict__ sx2, const float* __restrict__ sy2,
                                              float* __restrict__ out)
{
    __shared__ int keptList[2000];
    __shared__ int kcnt;
    int l = threadIdx.x;
    auto bw = [&](int w) -> u64 {
        const uint4* p = (const uint4*)(sInv + (size_t)w * 64);
        u64 v = 0;
#pragma unroll
        for (int j = 0; j < 16; ++j) {
            uint4 q = p[j];
            v |= ((u64)(q.x != 0) << (j * 4))     | ((u64)(q.y != 0) << (j * 4 + 1))
               | ((u64)(q.z != 0) << (j * 4 + 2)) | ((u64)(q.w != 0) << (j * 4 + 3));
        }
        return v;
    };
    // 64-bit uniform readlane helper (2x v_readlane_b32)
    auto rdlane64 = [&](u64 v, int src) -> u64 {
        u32 lo = __builtin_amdgcn_readlane((u32)v, src);
        u32 hi = __builtin_amdgcn_readlane((u32)(v >> 32), src);
        return ((u64)hi << 32) | lo;
    };
    u64 r0 = bw(l);
    u64 r1 = bw(64 + l);
    u64 r2 = (l < 32) ? bw(128 + l) : ~0ull;

    // depth-8 selfw prefetch ring in named registers (static, no array)
    u64 s0 = selfw[(size_t)0 * 64 + l];
    u64 s1 = selfw[(size_t)1 * 64 + l];
    u64 s2 = selfw[(size_t)2 * 64 + l];
    u64 s3 = selfw[(size_t)3 * 64 + l];
    u64 s4 = selfw[(size_t)4 * 64 + l];
    u64 s5 = selfw[(size_t)5 * 64 + l];
    u64 s6 = selfw[(size_t)6 * 64 + l];
    u64 s7 = selfw[(size_t)7 * 64 + l];

    int cnt = 0;
    bool done = false;
    for (int w = 0; w < 157; ++w) {
        u64 swreg = s0;
        s0 = s1; s1 = s2; s2 = s3; s3 = s4; s4 = s5; s5 = s6; s6 = s7;
        s7 = (w + 8 < 157) ? selfw[(size_t)(w + 8) * 64 + l] : 0ull;

        int slot = w >> 6, owner = w & 63;
        u64 val = (slot == 0) ? r0 : (slot == 1) ? r1 : r2;
        u64 rw = rdlane64(val, owner);
        u64 wmask = (w == 156) ? 0xFFFFull : ~0ull;
        u64 av = (~rw) & wmask;

        // ---- intra-word greedy resolve: scalar chain via readlane ----
        u64 km = 0;
        while (av) {
            int b = __builtin_ctzll(av);
            u64 sw = rdlane64(swreg, b);
            km |= 1ull << b;
            av &= ~(1ull << b);
            av &= ~sw;
        }
        // ---- commit: OR kept rows in batches of 16 (loads back-to-back) ----
        u64 kk = km;
        while (kk) {
            int bsx[16];
            int nb = 0;
            while (kk && nb < 16) {
                int b = __builtin_ctzll(kk);
                kk &= kk - 1;
                bsx[nb++] = b;
            }
            u64 a0 = 0, a1 = 0, a2 = 0;
#pragma unroll
            for (int u = 0; u < 16; ++u) {
                if (u < nb) {
                    int i = (w << 6) + bsx[u];
                    if (l == 0 && cnt + u < 2000) keptList[cnt + u] = i;
                    const u64* rp = rows + (size_t)i * NWORDS;
                    a0 |= rp[l];
                    a1 |= rp[64 + l];
                    if (l < 32) a2 |= rp[128 + l];
                }
            }
            r0 |= a0; r1 |= a1; r2 |= a2;
            cnt += nb;
            if (cnt >= 2000) { done = true; break; }
        }
        if (done) break;
    }
    if (l == 0) kcnt = (cnt < 2000) ? cnt : 2000;
    __syncthreads();
    int K = kcnt;
    for (int r = l; r < 2000; r += 64) {
        if (r < K) {
            int j = keptList[r];
            out[r * 4 + 0] = sx1[j];
            out[r * 4 + 1] = sy1[j];
            out[r * 4 + 2] = sx2[j];
            out[r * 4 + 3] = sy2[j];
            out[8000 + r]  = sS[j];
        } else {
            out[r * 4 + 0] = 0.f; out[r * 4 + 1] = 0.f;
            out[r * 4 + 2] = 0.f; out[r * 4 + 3] = 0.f;
            out[8000 + r]  = 0.f;
        }
    }
}

// ---------------------------------------------------------------------------
extern "C" void kernel_launch(void* const* d_in, const int* in_sizes, int n_in,
                              void* d_out, int out_size, void* d_ws, size_t ws_size,
                              hipStream_t stream)
{
    (void)in_sizes; (void)n_in; (void)out_size;
    const float* feat = (const float*)d_in[1];
    const float* wrpn = (const float*)d_in[3];
    const float* brpn = (const float*)d_in[4];
    const float* wcls = (const float*)d_in[5];
    const float* bcls = (const float*)d_in[6];
    const float* wreg = (const float*)d_in[7];
    const float* breg = (const float*)d_in[8];
    float* out = (float*)d_out;

    // K-split factor by workspace budget. need(ns) = ns*512*2560*4 + 16,252,928.
    int ns = (ws_size >= 58195968) ? 8 : (ws_size >= 37224448) ? 4 : 2;
    int cpt     = 8 / ns;                 // 64c-chunks per tap per z-slice
    int cptLog  = (ns == 2) ? 2 : (ns == 4) ? 1 : 0;
    int cptm1   = cpt - 1;
    int cptMul  = cpt * 64;               // c0base = bs * cptMul
    int niter   = 9 * cpt;
    size_t pkB = (size_t)ns * 512 * 2560 * 4;

    char* ws = (char*)d_ws;
    // Live ranges:
    //   [0,pkB)            pk     k1m..k2a
    //   [pkB,pkB+16.25M)   Xt+W   kprep..k1m; then smalls (k2a+), part
    //                      (k2a..k2b), rankp (k3a..k3b, aliases part/rows
    //                      region — part dead after k2b, memset after k3b),
    //                      rows (memset/k4..k5) share offsets.
    float* pk = (float*)ws;
    unsigned short* Xthi = (unsigned short*)(ws + pkB);
    unsigned short* Xtlo = Xthi + (size_t)52 * 64 * 512;
    unsigned short* Whi  = (unsigned short*)(ws + pkB + 6815744);
    unsigned short* Wlo  = Whi + (size_t)512 * 4608;

    char* sm = ws + pkB;
    float* score = (float*)(sm + 0);             // 90,000
    float* bx1   = (float*)(sm + 90000);
    float* by1   = (float*)(sm + 180000);
    float* bx2   = (float*)(sm + 270000);
    float* by2   = (float*)(sm + 360000);
    u32*   valid = (u32*)  (sm + 450000);        // 90,000
    u64*   key   = (u64*)  (sm + 540000);        // 180,000
    float* sS    = (float*)(sm + 1620000);       // 40,000
    float* sx1   = (float*)(sm + 1660000);
    float* sy1   = (float*)(sm + 1700000);
    float* sx2   = (float*)(sm + 1740000);
    float* sy2   = (float*)(sm + 1780000);
    u32*   sInv  = (u32*)  (sm + 1820000);       // 40,960
    u64*   selfw = (u64*)  (sm + 1860960);       // 81,920
    float4* sbox4= (float4*)(sm + 1942880);      // 163,840 (10240 entries)
    float* part  = (float*)(sm + 2106720);       // 3,600,000 (k2a..k2b)
    u32*   rankp = (u32*)  (sm + 2106720);       // 4,050,000 (k3a..k3b; after part dead)
    u64*   rows  = (u64*)  (sm + 2106720);       // 12,800,000 (k4..k5) -> ends sm+14.91M < 16.25M
    // peak footprint = pkB + 16,252,928 (ns=4 -> 37.2 MB, proven available)

    AnchorBase ab;
    {
        const float scales[3] = {128.f, 256.f, 512.f};
        const float aspect[3] = {0.5f, 1.f, 2.f};
        for (int ai = 0; ai < 3; ++ai) {
            float hr = sqrtf(aspect[ai]);
            float wratio = 1.0f / hr;
            for (int si = 0; si < 3; ++si) {
                float wsz = wratio * scales[si];
                float hsz = hr * scales[si];
                int a = ai * 3 + si;
                ab.b[a * 4 + 0] = rintf(-wsz / 2.0f);
                ab.b[a * 4 + 1] = rintf(-hsz / 2.0f);
                ab.b[a * 4 + 2] = rintf( wsz / 2.0f);
                ab.b[a * 4 + 3] = rintf( hsz / 2.0f);
            }
        }
    }

    kprep    <<<928, 256, 0, stream>>>(feat, wrpn, Xthi, Xtlo, Whi, Wlo);
    k1m      <<<dim3(4, 40, ns), 256, 0, stream>>>(Xthi, Xtlo, Whi, Wlo, pk,
                                                   cptLog, cptm1, cptMul, niter);
    k2a_heads<<<dim3(40, 8), 256, 0, stream>>>(pk, ns, brpn, wcls, wreg, part);
    k2b_decode<<<88, 256, 0, stream>>>(part, bcls, breg, ab, score, bx1, by1, bx2, by2, valid, key);
    k3a_rank <<<dim3(22, NJC), 256, 0, stream>>>(key, rankp);
    k3b_gather<<<88, 256, 0, stream>>>(rankp, score, bx1, by1, bx2, by2, valid,
                                       sS, sx1, sy1, sx2, sy2, sbox4, sInv);
    hipMemsetAsync(rows, 0, (size_t)PRE_TOPK * NWORDS * 8, stream);   // sub-diagonal + tail words
    k4_mat   <<<2500, 256, 0, stream>>>(sbox4, rows, selfw);
    k5_scan  <<<1, 64, 0, stream>>>(rows, selfw, sInv, sS, sx1, sy1, sx2, sy2, out);
}

// Round 8
// 335.849 us; speedup vs baseline: 1.1611x; 1.0287x over previous
//
#include <hip/hip_runtime.h>
#include <cmath>
#include <cstdint>
#include <cstddef>

typedef unsigned long long u64;
typedef unsigned int u32;

#define NPX   2500
#define NANCH 22500
#define PRE_TOPK 10000
#define NWORDS 160      // 160*64 = 10240 bits per NMS row
#define NJC 45          // k3a j-chunks (500 keys each)

struct AnchorBase { float b[36]; };

typedef __attribute__((ext_vector_type(8))) short bf16x8;
typedef __attribute__((ext_vector_type(4))) float f32x4;

__device__ inline unsigned short f2bf(float f) {
    u32 u = __float_as_uint(f);
    u32 r = u + 0x7fffu + ((u >> 16) & 1u);
    return (unsigned short)(r >> 16);
}
__device__ inline float bf2f(unsigned short h) {
    return __uint_as_float(((u32)h) << 16);
}

// async global->LDS 16B (global_load_lds_dwordx4). LDS dest must be
// wave-uniform base + lane*16 (verified for k1m: lds byte off == t*16+4096i).
__device__ inline void gload_lds16(const void* g, void* l) {
    __builtin_amdgcn_global_load_lds(
        (const __attribute__((address_space(1))) unsigned int*)g,
        (__attribute__((address_space(3))) unsigned int*)l, 16, 0, 0);
}

// ---------------------------------------------------------------------------
// KPREP: fused input prep (Xt bf16 hi/lo padded grid; W' bf16 hi/lo).
// ---------------------------------------------------------------------------
__global__ __launch_bounds__(256) void kprep(const float* __restrict__ feat,
                                             const float* __restrict__ wr,
                                             unsigned short* __restrict__ xthi,
                                             unsigned short* __restrict__ xtlo,
                                             unsigned short* __restrict__ whi,
                                             unsigned short* __restrict__ wlo)
{
    __shared__ float sh[4608];
    int bid = blockIdx.x;
    int t = threadIdx.x;
    if (bid < 416) {
        float (*tile)[65] = (float(*)[65])sh;
        int gr = bid >> 3;          // grid row 0..51
        int cc = bid & 7;           // c-chunk
        int tx = t & 63, ty = t >> 6;
        int y = gr - 1;
        bool rowok = (gr >= 1) && (gr <= 50);
#pragma unroll
        for (int i = 0; i < 16; ++i) {
            int c = i * 4 + ty;
            tile[c][tx] = (rowok && tx < 50)
                        ? feat[(size_t)(cc * 64 + c) * NPX + y * 50 + tx] : 0.f;
        }
        __syncthreads();
#pragma unroll
        for (int i = 0; i < 16; ++i) {
            int xp = i * 4 + ty;
            int cell = gr * 64 + xp;
            bool ok = rowok && xp >= 1 && xp <= 50;
            float v = ok ? tile[tx][xp - 1] : 0.f;
            unsigned short hi = f2bf(v);
            xthi[(size_t)cell * 512 + cc * 64 + tx] = hi;
            xtlo[(size_t)cell * 512 + cc * 64 + tx] = f2bf(v - bf2f(hi));
        }
    } else {
        int oc = bid - 416;         // 0..511
        for (int j = t; j < 4608; j += 256) sh[j] = wr[(size_t)oc * 4608 + j];
        __syncthreads();
        for (int k = t; k < 4608; k += 256) {
            int c = k & 511, tap = k >> 9;
            float v = sh[c * 9 + tap];
            unsigned short hi = f2bf(v);
            whi[(size_t)oc * 4608 + k] = hi;
            wlo[(size_t)oc * 4608 + k] = f2bf(v - bf2f(hi));
        }
    }
}

// ---------------------------------------------------------------------------
// K1m v8: v7 tiling (R7-verified) + global_load_lds staging (R18).
// v7 staged 48KB/iter via reg round-trips (bf16x8 load + ds_write): 553 MB
// total staging traffic through VGPRs + address VALU. The staging geometry
// is exactly the global_load_lds pattern: per-thread LDS byte offset
// = t*16 + 4096*i (wave-uniform base + lane*16), per-lane global address
// allowed. Replace all 12 round-trips/thread/iter with async
// global_load_lds_dwordx4 (m151: +35% at this tile scale; m193: width16
// +67% vs width4). Same bytes -> same LDS locations; compute untouched.
// ---------------------------------------------------------------------------
__global__ __launch_bounds__(256) void k1m(const unsigned short* __restrict__ xthi,
                                           const unsigned short* __restrict__ xtlo,
                                           const unsigned short* __restrict__ whi,
                                           const unsigned short* __restrict__ wlo,
                                           float* __restrict__ pk,
                                           int cptLog, int cptm1, int cptMul, int niter)
{
    __shared__ __align__(16) unsigned short Ah[8192];   // 128oc x 64k
    __shared__ __align__(16) unsigned short Al[8192];
    __shared__ __align__(16) unsigned short Bh[4096];   // 64px x 64k
    __shared__ __align__(16) unsigned short Bl[4096];

    int t = threadIdx.x;
    int lane = t & 63, wave = t >> 6;
    int wo = wave & 1, wp = wave >> 1;   // wo: 64-oc half, wp: 32-px half
    int ocb = blockIdx.x, pxb = blockIdx.y, bs = blockIdx.z;
    int q = lane >> 4, m = lane & 15;
    int c0base = bs * cptMul;

    // staging geometry: thread -> granule g (16B) of row r0 (+32i)
    int g  = t & 7;
    int r0 = t >> 3;                     // 0..31
    int ocA[4];
    int cellB[2];
#pragma unroll
    for (int i = 0; i < 4; ++i) ocA[i] = ocb * 128 + r0 + 32 * i;
#pragma unroll
    for (int i = 0; i < 2; ++i) {
        int opx = pxb * 64 + r0 + 32 * i;
        cellB[i] = (opx < NPX) ? ((opx / 50) + 1) * 64 + (opx % 50) + 1 : 190;
    }

    char* AhB = (char*)Ah;
    char* AlB = (char*)Al;
    char* BhB = (char*)Bh;
    char* BlB = (char*)Bl;
    int lb = t * 16;

    f32x4 acc[8];
    f32x4 zf = {0.f, 0.f, 0.f, 0.f};
#pragma unroll
    for (int i = 0; i < 8; ++i) acc[i] = zf;

    for (int it = 0; it < niter; ++it) {
        int tap = it >> cptLog;
        int cw  = it & cptm1;
        int c0  = c0base + cw * 64;
        int t3  = (tap * 43) >> 7;                      // tap/3
        int tapoff = (t3 - 1) * 64 + (tap - t3 * 3) - 1;
        // ---- stage 48KB: async global->LDS dwordx4, no VGPR round-trip ----
#pragma unroll
        for (int i = 0; i < 4; ++i) {
            size_t ga = (size_t)ocA[i] * 4608 + tap * 512 + c0 + g * 8;
            gload_lds16(whi + ga, AhB + lb + 4096 * i);
            gload_lds16(wlo + ga, AlB + lb + 4096 * i);
        }
#pragma unroll
        for (int i = 0; i < 2; ++i) {
            size_t gb = (size_t)(cellB[i] + tapoff) * 512 + c0 + g * 8;
            gload_lds16(xthi + gb, BhB + lb + 4096 * i);
            gload_lds16(xtlo + gb, BlB + lb + 4096 * i);
        }
        __syncthreads();
        // ---- compute: 2 k-steps of 32 ----
#pragma unroll
        for (int ks = 0; ks < 2; ++ks) {
            bf16x8 fah[4], fal[4], fbh[2], fbl[2];
#pragma unroll
            for (int mt = 0; mt < 4; ++mt) {
                int off = (wo * 64 + mt * 16 + m) * 64 + ks * 32 + q * 8;
                fah[mt] = *(const bf16x8*)(Ah + off);
                fal[mt] = *(const bf16x8*)(Al + off);
            }
#pragma unroll
            for (int nt = 0; nt < 2; ++nt) {
                int off = (wp * 32 + nt * 16 + m) * 64 + ks * 32 + q * 8;
                fbh[nt] = *(const bf16x8*)(Bh + off);
                fbl[nt] = *(const bf16x8*)(Bl + off);
            }
#pragma unroll
            for (int mt = 0; mt < 4; ++mt)
#pragma unroll
                for (int nt = 0; nt < 2; ++nt) {
                    f32x4 a = acc[mt * 2 + nt];
                    a = __builtin_amdgcn_mfma_f32_16x16x32_bf16(fal[mt], fbh[nt], a, 0, 0, 0);
                    a = __builtin_amdgcn_mfma_f32_16x16x32_bf16(fah[mt], fbl[nt], a, 0, 0, 0);
                    a = __builtin_amdgcn_mfma_f32_16x16x32_bf16(fah[mt], fbh[nt], a, 0, 0, 0);
                    acc[mt * 2 + nt] = a;
                }
        }
        __syncthreads();
    }
    // C/D: col(px)=lane&15, row(oc)=quad*4+reg
#pragma unroll
    for (int mt = 0; mt < 4; ++mt)
#pragma unroll
        for (int nt = 0; nt < 2; ++nt)
#pragma unroll
            for (int r = 0; r < 4; ++r) {
                int oc = ocb * 128 + wo * 64 + mt * 16 + q * 4 + r;
                int px = pxb * 64 + wp * 32 + nt * 16 + m;
                pk[((size_t)bs * 512 + oc) * 2560 + px] = acc[mt * 2 + nt][r];
            }
}

// ---------------------------------------------------------------------------
// K2a: fused k-split reduce + bias + ReLU + 1x1 heads partial GEMM.
// ---------------------------------------------------------------------------
__global__ __launch_bounds__(256) void k2a_heads(const float* __restrict__ pk, int ns,
                                                 const float* __restrict__ br,
                                                 const float* __restrict__ wcls,
                                                 const float* __restrict__ wreg,
                                                 float* __restrict__ part)
{
    __shared__ float vt[64 * 64];
    __shared__ float Wl[45 * 64];
    int t  = threadIdx.x;
    int pb = blockIdx.x;           // 0..39
    int s  = blockIdx.y;           // 0..7
    int cb = s * 64;
    for (int e = t; e < 45 * 64; e += 256) {
        int u = e >> 6, c = e & 63;
        Wl[e] = (u < 9) ? wcls[u * 512 + cb + c] : wreg[(u - 9) * 512 + cb + c];
    }
    int pxl = t & 63, ug = t >> 6;
    int px = pb * 64 + pxl;
    bool ok = px < NPX;
#pragma unroll
    for (int i = 0; i < 16; ++i) {
        int c = ug * 16 + i;       // wave-uniform
        float v = 0.f;
        if (ok) {
            size_t bidx = (size_t)(cb + c) * 2560 + px;
            v = br[cb + c];
            for (int ks = 0; ks < ns; ++ks) v += pk[(size_t)ks * 512 * 2560 + bidx];
            v = v > 0.f ? v : 0.f;
        }
        vt[c * 64 + pxl] = v;
    }
    __syncthreads();
    int ubase = ug * 12;
    int ulim  = (45 - ubase < 12) ? (45 - ubase) : 12;
    float acc[12];
#pragma unroll
    for (int j = 0; j < 12; ++j) acc[j] = 0.f;
    for (int c = 0; c < 64; ++c) {
        float v = vt[c * 64 + pxl];
#pragma unroll
        for (int j = 0; j < 12; ++j)
            acc[j] = fmaf(v, Wl[(ubase + j) * 64 + c], acc[j]);
    }
    if (ok) {
        for (int j = 0; j < ulim; ++j)
            part[((size_t)s * 45 + ubase + j) * NPX + px] = acc[j];
    }
}

// ---------------------------------------------------------------------------
// K2b: reduce partials + bias, sigmoid, decode, clip, validity, sort key.
// ---------------------------------------------------------------------------
__global__ __launch_bounds__(256) void k2b_decode(const float* __restrict__ part,
                                                  const float* __restrict__ bcls,
                                                  const float* __restrict__ breg,
                                                  AnchorBase ab,
                                                  float* __restrict__ score,
                                                  float* __restrict__ bx1, float* __restrict__ by1,
                                                  float* __restrict__ bx2, float* __restrict__ by2,
                                                  u32* __restrict__ valid,
                                                  u64* __restrict__ key)
{
    int id = blockIdx.x * 256 + threadIdx.x;
    if (id >= NANCH) return;
    int k  = id / NPX;
    int px = id - k * NPX;

    float z  = bcls[k];
    float d0 = breg[k * 4 + 0], d1 = breg[k * 4 + 1];
    float d2 = breg[k * 4 + 2], d3 = breg[k * 4 + 3];
#pragma unroll
    for (int s = 0; s < 8; ++s) {
        const float* p = part + (size_t)s * 45 * NPX;
        z  += p[(size_t)k * NPX + px];
        d0 += p[(size_t)(9 + k * 4 + 0) * NPX + px];
        d1 += p[(size_t)(9 + k * 4 + 1) * NPX + px];
        d2 += p[(size_t)(9 + k * 4 + 2) * NPX + px];
        d3 += p[(size_t)(9 + k * 4 + 3) * NPX + px];
    }
    float sc = 1.f / (1.f + expf(-z));

    int yy = px / 50, xx = px - (px / 50) * 50;
    float fx = (float)xx, fy = (float)yy;
    float ax1 = fx + ab.b[k * 4 + 0], ay1 = fy + ab.b[k * 4 + 1];
    float ax2 = fx + ab.b[k * 4 + 2], ay2 = fy + ab.b[k * 4 + 3];
    float aw = ax2 - ax1, ah = ay2 - ay1;
    float cx = ax1 + 0.5f * aw, cy = ay1 + 0.5f * ah;
    float pcx = d0 * aw + cx, pcy = d1 * ah + cy;
    float pw = expf(d2) * aw, ph = expf(d3) * ah;
    float x1 = pcx - 0.5f * pw, y1 = pcy - 0.5f * ph;
    float x2 = pcx + 0.5f * pw, y2 = pcy + 0.5f * ph;
    x1 = fminf(fmaxf(x1, 0.f), 800.f);
    y1 = fminf(fmaxf(y1, 0.f), 800.f);
    x2 = fminf(fmaxf(x2, 0.f), 800.f);
    y2 = fminf(fmaxf(y2, 0.f), 800.f);
    u32 v = ((x2 - x1) >= 16.f) && ((y2 - y1) >= 16.f);

    int f = px * 9 + k;
    score[f] = sc;
    bx1[f] = x1; by1[f] = y1; bx2[f] = x2; by2[f] = y2;
    valid[f] = v;
    u32 sb = __float_as_uint(sc);
    key[f] = ((u64)(~sb) << 32) | (u32)f;
}

// ---------------------------------------------------------------------------
// K3a v5: u64 all-pairs partial ranks, re-gridded for occupancy (R17 WIN).
// 22x45 = 990 blocks ~ 15 waves/CU. Verified R7: dropped out of top-5.
// ---------------------------------------------------------------------------
__global__ __launch_bounds__(256) void k3a_rank(const u64* __restrict__ key,
                                                u32* __restrict__ rankp)
{
    __shared__ __align__(16) u64 sk[500];
    int t  = threadIdx.x;
    int jb = blockIdx.y;           // 0..44
    int jLo = jb * 500;
    for (int e = t; e < 500; e += 256) sk[e] = key[jLo + e];
    __syncthreads();
    int i0 = blockIdx.x * 1024 + t;
    int i1 = i0 + 256, i2 = i0 + 512, i3 = i0 + 768;
    u64 k0 = (i0 < NANCH) ? key[i0] : 0ull;
    u64 k1 = (i1 < NANCH) ? key[i1] : 0ull;
    u64 k2 = (i2 < NANCH) ? key[i2] : 0ull;
    u64 k3 = (i3 < NANCH) ? key[i3] : 0ull;
    u32 c0 = 0, c1 = 0, c2 = 0, c3 = 0;
    const ulonglong2* sk2 = (const ulonglong2*)sk;
#pragma unroll 5
    for (int j = 0; j < 250; ++j) {
        ulonglong2 v = sk2[j];
        c0 += (v.x < k0) ? 1u : 0u;  c0 += (v.y < k0) ? 1u : 0u;
        c1 += (v.x < k1) ? 1u : 0u;  c1 += (v.y < k1) ? 1u : 0u;
        c2 += (v.x < k2) ? 1u : 0u;  c2 += (v.y < k2) ? 1u : 0u;
        c3 += (v.x < k3) ? 1u : 0u;  c3 += (v.y < k3) ? 1u : 0u;
    }
    size_t base = (size_t)jb * NANCH;
    if (i0 < NANCH) rankp[base + i0] = c0;
    if (i1 < NANCH) rankp[base + i1] = c1;
    if (i2 < NANCH) rankp[base + i2] = c2;
    if (i3 < NANCH) rankp[base + i3] = c3;
}

// ---------------------------------------------------------------------------
// K3b: sum 45 partial ranks, scatter top-10000 (+ packed float4 boxes);
// sInv[r] = 1 if invalid box.
// ---------------------------------------------------------------------------
__global__ __launch_bounds__(256) void k3b_gather(const u32* __restrict__ rankp,
                                                  const float* __restrict__ score,
                                                  const float* __restrict__ bx1, const float* __restrict__ by1,
                                                  const float* __restrict__ bx2, const float* __restrict__ by2,
                                                  const u32* __restrict__ valid,
                                                  float* __restrict__ sS,
                                                  float* __restrict__ sx1, float* __restrict__ sy1,
                                                  float* __restrict__ sx2, float* __restrict__ sy2,
                                                  float4* __restrict__ sbox4,
                                                  u32* __restrict__ sInv)
{
    int i = blockIdx.x * 256 + threadIdx.x;
    if (i >= NANCH) return;
    u32 r = 0;
#pragma unroll
    for (int c = 0; c < NJC; ++c) r += rankp[(size_t)c * NANCH + i];
    if (r >= PRE_TOPK) return;
    float x1 = bx1[i], y1 = by1[i], x2 = bx2[i], y2 = by2[i];
    sS[r] = score[i];
    sx1[r] = x1; sy1[r] = y1; sx2[r] = x2; sy2[r] = y2;
    float4 b4; b4.x = x1; b4.y = y1; b4.z = x2; b4.w = y2;
    sbox4[r] = b4;
    sInv[r] = valid[i] ? 0u : 1u;
}

// ---------------------------------------------------------------------------
// K4 v4: row-per-wave suppression matrix (R10 — verified, ~20us).
// ---------------------------------------------------------------------------
__global__ __launch_bounds__(256) void k4_mat(const float4* __restrict__ sbox4,
                                              u64* __restrict__ rows,
                                              u64* __restrict__ selfw)
{
    int t = threadIdx.x, lane = t & 63, wave = t >> 6;
    int i = blockIdx.x * 4 + wave;
    if (i >= PRE_TOPK) return;
    float4 bi = sbox4[i];                       // wave-uniform, loaded once
    float ai = (bi.z - bi.x) * (bi.w - bi.y);
    int wd  = i >> 6;
    int ish = i & 63;
    u64 diagmask = ~((2ull << ish) - 1ull);     // ish=63 -> 0 (no j>i in word)
    u64* rowp = rows + (size_t)i * NWORDS;
    for (int w = wd; w < 157; ++w) {
        float4 bj = sbox4[(w << 6) + lane];     // coalesced dwordx4
        float xx1 = fmaxf(bi.x, bj.x);
        float yy1 = fmaxf(bi.y, bj.y);
        float xx2 = fminf(bi.z, bj.z);
        float yy2 = fminf(bi.w, bj.w);
        float iw = fmaxf(xx2 - xx1, 0.f);
        float ih = fmaxf(yy2 - yy1, 0.f);
        float inter = iw * ih;
        float aj = (bj.z - bj.x) * (bj.w - bj.y);
        float uni = ai + aj - inter;
        u64 b = __ballot(inter > 0.7f * uni);
        if (w == wd)  b &= diagmask;
        if (w == 156) b &= 0xFFFFull;
        if (lane == 0) {
            rowp[w] = b;
            if (w == wd) selfw[i] = b;
        }
    }
}

// ---------------------------------------------------------------------------
// K5 v6 (R3-verified ~66us — FINAL): word-scan + scalar readlane resolve +
// batch-16 commit. R14/R15 restructures both regressed; latency-wait-bound
// at this structure. Do not touch.
// ---------------------------------------------------------------------------
__global__ __launch_bounds__(64) void k5_scan(const u64* __restrict__ rows,
                                              const u64* __restrict__ selfw,
                                              const u32* __restrict__ sInv,
                                              const float* __restrict__ sS,
                                              const float* __restrict__ sx1, const float* __restrict__ sy1,
                                              const float* __restrict__ sx2, const float* __restrict__ sy2,
                                              float* __restrict__ out)
{
    __shared__ int keptList[2000];
    __shared__ int kcnt;
    int l = threadIdx.x;
    auto bw = [&](int w) -> u64 {
        const uint4* p = (const uint4*)(sInv + (size_t)w * 64);
        u64 v = 0;
#pragma unroll
        for (int j = 0; j < 16; ++j) {
            uint4 q = p[j];
            v |= ((u64)(q.x != 0) << (j * 4))     | ((u64)(q.y != 0) << (j * 4 + 1))
               | ((u64)(q.z != 0) << (j * 4 + 2)) | ((u64)(q.w != 0) << (j * 4 + 3));
        }
        return v;
    };
    // 64-bit uniform readlane helper (2x v_readlane_b32)
    auto rdlane64 = [&](u64 v, int src) -> u64 {
        u32 lo = __builtin_amdgcn_readlane((u32)v, src);
        u32 hi = __builtin_amdgcn_readlane((u32)(v >> 32), src);
        return ((u64)hi << 32) | lo;
    };
    u64 r0 = bw(l);
    u64 r1 = bw(64 + l);
    u64 r2 = (l < 32) ? bw(128 + l) : ~0ull;

    // depth-8 selfw prefetch ring in named registers (static, no array)
    u64 s0 = selfw[(size_t)0 * 64 + l];
    u64 s1 = selfw[(size_t)1 * 64 + l];
    u64 s2 = selfw[(size_t)2 * 64 + l];
    u64 s3 = selfw[(size_t)3 * 64 + l];
    u64 s4 = selfw[(size_t)4 * 64 + l];
    u64 s5 = selfw[(size_t)5 * 64 + l];
    u64 s6 = selfw[(size_t)6 * 64 + l];
    u64 s7 = selfw[(size_t)7 * 64 + l];

    int cnt = 0;
    bool done = false;
    for (int w = 0; w < 157; ++w) {
        u64 swreg = s0;
        s0 = s1; s1 = s2; s2 = s3; s3 = s4; s4 = s5; s5 = s6; s6 = s7;
        s7 = (w + 8 < 157) ? selfw[(size_t)(w + 8) * 64 + l] : 0ull;

        int slot = w >> 6, owner = w & 63;
        u64 val = (slot == 0) ? r0 : (slot == 1) ? r1 : r2;
        u64 rw = rdlane64(val, owner);
        u64 wmask = (w == 156) ? 0xFFFFull : ~0ull;
        u64 av = (~rw) & wmask;

        // ---- intra-word greedy resolve: scalar chain via readlane ----
        u64 km = 0;
        while (av) {
            int b = __builtin_ctzll(av);
            u64 sw = rdlane64(swreg, b);
            km |= 1ull << b;
            av &= ~(1ull << b);
            av &= ~sw;
        }
        // ---- commit: OR kept rows in batches of 16 (loads back-to-back) ----
        u64 kk = km;
        while (kk) {
            int bsx[16];
            int nb = 0;
            while (kk && nb < 16) {
                int b = __builtin_ctzll(kk);
                kk &= kk - 1;
                bsx[nb++] = b;
            }
            u64 a0 = 0, a1 = 0, a2 = 0;
#pragma unroll
            for (int u = 0; u < 16; ++u) {
                if (u < nb) {
                    int i = (w << 6) + bsx[u];
                    if (l == 0 && cnt + u < 2000) keptList[cnt + u] = i;
                    const u64* rp = rows + (size_t)i * NWORDS;
                    a0 |= rp[l];
                    a1 |= rp[64 + l];
                    if (l < 32) a2 |= rp[128 + l];
                }
            }
            r0 |= a0; r1 |= a1; r2 |= a2;
            cnt += nb;
            if (cnt >= 2000) { done = true; break; }
        }
        if (done) break;
    }
    if (l == 0) kcnt = (cnt < 2000) ? cnt : 2000;
    __syncthreads();
    int K = kcnt;
    for (int r = l; r < 2000; r += 64) {
        if (r < K) {
            int j = keptList[r];
            out[r * 4 + 0] = sx1[j];
            out[r * 4 + 1] = sy1[j];
            out[r * 4 + 2] = sx2[j];
            out[r * 4 + 3] = sy2[j];
            out[8000 + r]  = sS[j];
        } else {
            out[r * 4 + 0] = 0.f; out[r * 4 + 1] = 0.f;
            out[r * 4 + 2] = 0.f; out[r * 4 + 3] = 0.f;
            out[8000 + r]  = 0.f;
        }
    }
}

// ---------------------------------------------------------------------------
extern "C" void kernel_launch(void* const* d_in, const int* in_sizes, int n_in,
                              void* d_out, int out_size, void* d_ws, size_t ws_size,
                              hipStream_t stream)
{
    (void)in_sizes; (void)n_in; (void)out_size;
    const float* feat = (const float*)d_in[1];
    const float* wrpn = (const float*)d_in[3];
    const float* brpn = (const float*)d_in[4];
    const float* wcls = (const float*)d_in[5];
    const float* bcls = (const float*)d_in[6];
    const float* wreg = (const float*)d_in[7];
    const float* breg = (const float*)d_in[8];
    float* out = (float*)d_out;

    // K-split factor by workspace budget. need(ns) = ns*512*2560*4 + 16,252,928.
    int ns = (ws_size >= 58195968) ? 8 : (ws_size >= 37224448) ? 4 : 2;
    int cpt     = 8 / ns;                 // 64c-chunks per tap per z-slice
    int cptLog  = (ns == 2) ? 2 : (ns == 4) ? 1 : 0;
    int cptm1   = cpt - 1;
    int cptMul  = cpt * 64;               // c0base = bs * cptMul
    int niter   = 9 * cpt;
    size_t pkB = (size_t)ns * 512 * 2560 * 4;

    char* ws = (char*)d_ws;
    // Live ranges:
    //   [0,pkB)            pk     k1m..k2a
    //   [pkB,pkB+16.25M)   Xt+W   kprep..k1m; then smalls (k2a+), part
    //                      (k2a..k2b), rankp (k3a..k3b, aliases part/rows
    //                      region — part dead after k2b, memset after k3b),
    //                      rows (memset/k4..k5) share offsets.
    float* pk = (float*)ws;
    unsigned short* Xthi = (unsigned short*)(ws + pkB);
    unsigned short* Xtlo = Xthi + (size_t)52 * 64 * 512;
    unsigned short* Whi  = (unsigned short*)(ws + pkB + 6815744);
    unsigned short* Wlo  = Whi + (size_t)512 * 4608;

    char* sm = ws + pkB;
    float* score = (float*)(sm + 0);             // 90,000
    float* bx1   = (float*)(sm + 90000);
    float* by1   = (float*)(sm + 180000);
    float* bx2   = (float*)(sm + 270000);
    float* by2   = (float*)(sm + 360000);
    u32*   valid = (u32*)  (sm + 450000);        // 90,000
    u64*   key   = (u64*)  (sm + 540000);        // 180,000
    float* sS    = (float*)(sm + 1620000);       // 40,000
    float* sx1   = (float*)(sm + 1660000);
    float* sy1   = (float*)(sm + 1700000);
    float* sx2   = (float*)(sm + 1740000);
    float* sy2   = (float*)(sm + 1780000);
    u32*   sInv  = (u32*)  (sm + 1820000);       // 40,960
    u64*   selfw = (u64*)  (sm + 1860960);       // 81,920
    float4* sbox4= (float4*)(sm + 1942880);      // 163,840 (10240 entries)
    float* part  = (float*)(sm + 2106720);       // 3,600,000 (k2a..k2b)
    u32*   rankp = (u32*)  (sm + 2106720);       // 4,050,000 (k3a..k3b; after part dead)
    u64*   rows  = (u64*)  (sm + 2106720);       // 12,800,000 (k4..k5) -> ends sm+14.91M < 16.25M
    // peak footprint = pkB + 16,252,928 (ns=4 -> 37.2 MB, proven available)

    AnchorBase ab;
    {
        const float scales[3] = {128.f, 256.f, 512.f};
        const float aspect[3] = {0.5f, 1.f, 2.f};
        for (int ai = 0; ai < 3; ++ai) {
            float hr = sqrtf(aspect[ai]);
            float wratio = 1.0f / hr;
            for (int si = 0; si < 3; ++si) {
                float wsz = wratio * scales[si];
                float hsz = hr * scales[si];
                int a = ai * 3 + si;
                ab.b[a * 4 + 0] = rintf(-wsz / 2.0f);
                ab.b[a * 4 + 1] = rintf(-hsz / 2.0f);
                ab.b[a * 4 + 2] = rintf( wsz / 2.0f);
                ab.b[a * 4 + 3] = rintf( hsz / 2.0f);
            }
        }
    }

    kprep    <<<928, 256, 0, stream>>>(feat, wrpn, Xthi, Xtlo, Whi, Wlo);
    k1m      <<<dim3(4, 40, ns), 256, 0, stream>>>(Xthi, Xtlo, Whi, Wlo, pk,
                                                   cptLog, cptm1, cptMul, niter);
    k2a_heads<<<dim3(40, 8), 256, 0, stream>>>(pk, ns, brpn, wcls, wreg, part);
    k2b_decode<<<88, 256, 0, stream>>>(part, bcls, breg, ab, score, bx1, by1, bx2, by2, valid, key);
    k3a_rank <<<dim3(22, NJC), 256, 0, stream>>>(key, rankp);
    k3b_gather<<<88, 256, 0, stream>>>(rankp, score, bx1, by1, bx2, by2, valid,
                                       sS, sx1, sy1, sx2, sy2, sbox4, sInv);
    hipMemsetAsync(rows, 0, (size_t)PRE_TOPK * NWORDS * 8, stream);   // sub-diagonal + tail words
    k4_mat   <<<2500, 256, 0, stream>>>(sbox4, rows, selfw);
    k5_scan  <<<1, 64, 0, stream>>>(rows, selfw, sInv, sS, sx1, sy1, sx2, sy2, out);
}

// Round 9
// 332.958 us; speedup vs baseline: 1.1712x; 1.0087x over previous
//
#include <hip/hip_runtime.h>
#include <cmath>
#include <cstdint>
#include <cstddef>

typedef unsigned long long u64;
typedef unsigned int u32;

#define NPX   2500
#define NANCH 22500
#define PRE_TOPK 10000
#define NWORDS 160      // 160*64 = 10240 bits per NMS row
#define NJC 45          // k3a j-chunks (500 keys each)

struct AnchorBase { float b[36]; };

typedef __attribute__((ext_vector_type(8))) short bf16x8;
typedef __attribute__((ext_vector_type(4))) float f32x4;

__device__ inline unsigned short f2bf(float f) {
    u32 u = __float_as_uint(f);
    u32 r = u + 0x7fffu + ((u >> 16) & 1u);
    return (unsigned short)(r >> 16);
}
__device__ inline float bf2f(unsigned short h) {
    return __uint_as_float(((u32)h) << 16);
}

// async global->LDS 16B (global_load_lds_dwordx4). LDS dest must be
// wave-uniform base + lane*16 (verified for k1m: lds byte off == t*16+4096i).
__device__ inline void gload_lds16(const void* g, void* l) {
    __builtin_amdgcn_global_load_lds(
        (const __attribute__((address_space(1))) unsigned int*)g,
        (__attribute__((address_space(3))) unsigned int*)l, 16, 0, 0);
}

// ---------------------------------------------------------------------------
// KPREP: fused input prep (Xt bf16 hi/lo padded grid; W' bf16 hi/lo).
// ---------------------------------------------------------------------------
__global__ __launch_bounds__(256) void kprep(const float* __restrict__ feat,
                                             const float* __restrict__ wr,
                                             unsigned short* __restrict__ xthi,
                                             unsigned short* __restrict__ xtlo,
                                             unsigned short* __restrict__ whi,
                                             unsigned short* __restrict__ wlo)
{
    __shared__ float sh[4608];
    int bid = blockIdx.x;
    int t = threadIdx.x;
    if (bid < 416) {
        float (*tile)[65] = (float(*)[65])sh;
        int gr = bid >> 3;          // grid row 0..51
        int cc = bid & 7;           // c-chunk
        int tx = t & 63, ty = t >> 6;
        int y = gr - 1;
        bool rowok = (gr >= 1) && (gr <= 50);
#pragma unroll
        for (int i = 0; i < 16; ++i) {
            int c = i * 4 + ty;
            tile[c][tx] = (rowok && tx < 50)
                        ? feat[(size_t)(cc * 64 + c) * NPX + y * 50 + tx] : 0.f;
        }
        __syncthreads();
#pragma unroll
        for (int i = 0; i < 16; ++i) {
            int xp = i * 4 + ty;
            int cell = gr * 64 + xp;
            bool ok = rowok && xp >= 1 && xp <= 50;
            float v = ok ? tile[tx][xp - 1] : 0.f;
            unsigned short hi = f2bf(v);
            xthi[(size_t)cell * 512 + cc * 64 + tx] = hi;
            xtlo[(size_t)cell * 512 + cc * 64 + tx] = f2bf(v - bf2f(hi));
        }
    } else {
        int oc = bid - 416;         // 0..511
        for (int j = t; j < 4608; j += 256) sh[j] = wr[(size_t)oc * 4608 + j];
        __syncthreads();
        for (int k = t; k < 4608; k += 256) {
            int c = k & 511, tap = k >> 9;
            float v = sh[c * 9 + tap];
            unsigned short hi = f2bf(v);
            whi[(size_t)oc * 4608 + k] = hi;
            wlo[(size_t)oc * 4608 + k] = f2bf(v - bf2f(hi));
        }
    }
}

// ---------------------------------------------------------------------------
// K1m v8: v7 tiling + global_load_lds staging (R8-verified WIN, -9.7us).
// ---------------------------------------------------------------------------
__global__ __launch_bounds__(256) void k1m(const unsigned short* __restrict__ xthi,
                                           const unsigned short* __restrict__ xtlo,
                                           const unsigned short* __restrict__ whi,
                                           const unsigned short* __restrict__ wlo,
                                           float* __restrict__ pk,
                                           int cptLog, int cptm1, int cptMul, int niter)
{
    __shared__ __align__(16) unsigned short Ah[8192];   // 128oc x 64k
    __shared__ __align__(16) unsigned short Al[8192];
    __shared__ __align__(16) unsigned short Bh[4096];   // 64px x 64k
    __shared__ __align__(16) unsigned short Bl[4096];

    int t = threadIdx.x;
    int lane = t & 63, wave = t >> 6;
    int wo = wave & 1, wp = wave >> 1;   // wo: 64-oc half, wp: 32-px half
    int ocb = blockIdx.x, pxb = blockIdx.y, bs = blockIdx.z;
    int q = lane >> 4, m = lane & 15;
    int c0base = bs * cptMul;

    // staging geometry: thread -> granule g (16B) of row r0 (+32i)
    int g  = t & 7;
    int r0 = t >> 3;                     // 0..31
    int ocA[4];
    int cellB[2];
#pragma unroll
    for (int i = 0; i < 4; ++i) ocA[i] = ocb * 128 + r0 + 32 * i;
#pragma unroll
    for (int i = 0; i < 2; ++i) {
        int opx = pxb * 64 + r0 + 32 * i;
        cellB[i] = (opx < NPX) ? ((opx / 50) + 1) * 64 + (opx % 50) + 1 : 190;
    }

    char* AhB = (char*)Ah;
    char* AlB = (char*)Al;
    char* BhB = (char*)Bh;
    char* BlB = (char*)Bl;
    int lb = t * 16;

    f32x4 acc[8];
    f32x4 zf = {0.f, 0.f, 0.f, 0.f};
#pragma unroll
    for (int i = 0; i < 8; ++i) acc[i] = zf;

    for (int it = 0; it < niter; ++it) {
        int tap = it >> cptLog;
        int cw  = it & cptm1;
        int c0  = c0base + cw * 64;
        int t3  = (tap * 43) >> 7;                      // tap/3
        int tapoff = (t3 - 1) * 64 + (tap - t3 * 3) - 1;
        // ---- stage 48KB: async global->LDS dwordx4, no VGPR round-trip ----
#pragma unroll
        for (int i = 0; i < 4; ++i) {
            size_t ga = (size_t)ocA[i] * 4608 + tap * 512 + c0 + g * 8;
            gload_lds16(whi + ga, AhB + lb + 4096 * i);
            gload_lds16(wlo + ga, AlB + lb + 4096 * i);
        }
#pragma unroll
        for (int i = 0; i < 2; ++i) {
            size_t gb = (size_t)(cellB[i] + tapoff) * 512 + c0 + g * 8;
            gload_lds16(xthi + gb, BhB + lb + 4096 * i);
            gload_lds16(xtlo + gb, BlB + lb + 4096 * i);
        }
        __syncthreads();
        // ---- compute: 2 k-steps of 32 ----
#pragma unroll
        for (int ks = 0; ks < 2; ++ks) {
            bf16x8 fah[4], fal[4], fbh[2], fbl[2];
#pragma unroll
            for (int mt = 0; mt < 4; ++mt) {
                int off = (wo * 64 + mt * 16 + m) * 64 + ks * 32 + q * 8;
                fah[mt] = *(const bf16x8*)(Ah + off);
                fal[mt] = *(const bf16x8*)(Al + off);
            }
#pragma unroll
            for (int nt = 0; nt < 2; ++nt) {
                int off = (wp * 32 + nt * 16 + m) * 64 + ks * 32 + q * 8;
                fbh[nt] = *(const bf16x8*)(Bh + off);
                fbl[nt] = *(const bf16x8*)(Bl + off);
            }
#pragma unroll
            for (int mt = 0; mt < 4; ++mt)
#pragma unroll
                for (int nt = 0; nt < 2; ++nt) {
                    f32x4 a = acc[mt * 2 + nt];
                    a = __builtin_amdgcn_mfma_f32_16x16x32_bf16(fal[mt], fbh[nt], a, 0, 0, 0);
                    a = __builtin_amdgcn_mfma_f32_16x16x32_bf16(fah[mt], fbl[nt], a, 0, 0, 0);
                    a = __builtin_amdgcn_mfma_f32_16x16x32_bf16(fah[mt], fbh[nt], a, 0, 0, 0);
                    acc[mt * 2 + nt] = a;
                }
        }
        __syncthreads();
    }
    // C/D: col(px)=lane&15, row(oc)=quad*4+reg
#pragma unroll
    for (int mt = 0; mt < 4; ++mt)
#pragma unroll
        for (int nt = 0; nt < 2; ++nt)
#pragma unroll
            for (int r = 0; r < 4; ++r) {
                int oc = ocb * 128 + wo * 64 + mt * 16 + q * 4 + r;
                int px = pxb * 64 + wp * 32 + nt * 16 + m;
                pk[((size_t)bs * 512 + oc) * 2560 + px] = acc[mt * 2 + nt][r];
            }
}

// ---------------------------------------------------------------------------
// K2a: fused k-split reduce + bias + ReLU + 1x1 heads partial GEMM.
// ---------------------------------------------------------------------------
__global__ __launch_bounds__(256) void k2a_heads(const float* __restrict__ pk, int ns,
                                                 const float* __restrict__ br,
                                                 const float* __restrict__ wcls,
                                                 const float* __restrict__ wreg,
                                                 float* __restrict__ part)
{
    __shared__ float vt[64 * 64];
    __shared__ float Wl[45 * 64];
    int t  = threadIdx.x;
    int pb = blockIdx.x;           // 0..39
    int s  = blockIdx.y;           // 0..7
    int cb = s * 64;
    for (int e = t; e < 45 * 64; e += 256) {
        int u = e >> 6, c = e & 63;
        Wl[e] = (u < 9) ? wcls[u * 512 + cb + c] : wreg[(u - 9) * 512 + cb + c];
    }
    int pxl = t & 63, ug = t >> 6;
    int px = pb * 64 + pxl;
    bool ok = px < NPX;
#pragma unroll
    for (int i = 0; i < 16; ++i) {
        int c = ug * 16 + i;       // wave-uniform
        float v = 0.f;
        if (ok) {
            size_t bidx = (size_t)(cb + c) * 2560 + px;
            v = br[cb + c];
            for (int ks = 0; ks < ns; ++ks) v += pk[(size_t)ks * 512 * 2560 + bidx];
            v = v > 0.f ? v : 0.f;
        }
        vt[c * 64 + pxl] = v;
    }
    __syncthreads();
    int ubase = ug * 12;
    int ulim  = (45 - ubase < 12) ? (45 - ubase) : 12;
    float acc[12];
#pragma unroll
    for (int j = 0; j < 12; ++j) acc[j] = 0.f;
    for (int c = 0; c < 64; ++c) {
        float v = vt[c * 64 + pxl];
#pragma unroll
        for (int j = 0; j < 12; ++j)
            acc[j] = fmaf(v, Wl[(ubase + j) * 64 + c], acc[j]);
    }
    if (ok) {
        for (int j = 0; j < ulim; ++j)
            part[((size_t)s * 45 + ubase + j) * NPX + px] = acc[j];
    }
}

// ---------------------------------------------------------------------------
// K2b: reduce partials + bias, sigmoid, decode, clip, validity, sort key.
// ---------------------------------------------------------------------------
__global__ __launch_bounds__(256) void k2b_decode(const float* __restrict__ part,
                                                  const float* __restrict__ bcls,
                                                  const float* __restrict__ breg,
                                                  AnchorBase ab,
                                                  float* __restrict__ score,
                                                  float* __restrict__ bx1, float* __restrict__ by1,
                                                  float* __restrict__ bx2, float* __restrict__ by2,
                                                  u32* __restrict__ valid,
                                                  u64* __restrict__ key)
{
    int id = blockIdx.x * 256 + threadIdx.x;
    if (id >= NANCH) return;
    int k  = id / NPX;
    int px = id - k * NPX;

    float z  = bcls[k];
    float d0 = breg[k * 4 + 0], d1 = breg[k * 4 + 1];
    float d2 = breg[k * 4 + 2], d3 = breg[k * 4 + 3];
#pragma unroll
    for (int s = 0; s < 8; ++s) {
        const float* p = part + (size_t)s * 45 * NPX;
        z  += p[(size_t)k * NPX + px];
        d0 += p[(size_t)(9 + k * 4 + 0) * NPX + px];
        d1 += p[(size_t)(9 + k * 4 + 1) * NPX + px];
        d2 += p[(size_t)(9 + k * 4 + 2) * NPX + px];
        d3 += p[(size_t)(9 + k * 4 + 3) * NPX + px];
    }
    float sc = 1.f / (1.f + expf(-z));

    int yy = px / 50, xx = px - (px / 50) * 50;
    float fx = (float)xx, fy = (float)yy;
    float ax1 = fx + ab.b[k * 4 + 0], ay1 = fy + ab.b[k * 4 + 1];
    float ax2 = fx + ab.b[k * 4 + 2], ay2 = fy + ab.b[k * 4 + 3];
    float aw = ax2 - ax1, ah = ay2 - ay1;
    float cx = ax1 + 0.5f * aw, cy = ay1 + 0.5f * ah;
    float pcx = d0 * aw + cx, pcy = d1 * ah + cy;
    float pw = expf(d2) * aw, ph = expf(d3) * ah;
    float x1 = pcx - 0.5f * pw, y1 = pcy - 0.5f * ph;
    float x2 = pcx + 0.5f * pw, y2 = pcy + 0.5f * ph;
    x1 = fminf(fmaxf(x1, 0.f), 800.f);
    y1 = fminf(fmaxf(y1, 0.f), 800.f);
    x2 = fminf(fmaxf(x2, 0.f), 800.f);
    y2 = fminf(fmaxf(y2, 0.f), 800.f);
    u32 v = ((x2 - x1) >= 16.f) && ((y2 - y1) >= 16.f);

    int f = px * 9 + k;
    score[f] = sc;
    bx1[f] = x1; by1[f] = y1; bx2[f] = x2; by2[f] = y2;
    valid[f] = v;
    u32 sb = __float_as_uint(sc);
    key[f] = ((u64)(~sb) << 32) | (u32)f;
}

// ---------------------------------------------------------------------------
// K3a v5: u64 all-pairs partial ranks, re-gridded for occupancy (R7 WIN).
// 22x45 = 990 blocks ~ 15 waves/CU. Verified R7: dropped out of top-5.
// ---------------------------------------------------------------------------
__global__ __launch_bounds__(256) void k3a_rank(const u64* __restrict__ key,
                                                u32* __restrict__ rankp)
{
    __shared__ __align__(16) u64 sk[500];
    int t  = threadIdx.x;
    int jb = blockIdx.y;           // 0..44
    int jLo = jb * 500;
    for (int e = t; e < 500; e += 256) sk[e] = key[jLo + e];
    __syncthreads();
    int i0 = blockIdx.x * 1024 + t;
    int i1 = i0 + 256, i2 = i0 + 512, i3 = i0 + 768;
    u64 k0 = (i0 < NANCH) ? key[i0] : 0ull;
    u64 k1 = (i1 < NANCH) ? key[i1] : 0ull;
    u64 k2 = (i2 < NANCH) ? key[i2] : 0ull;
    u64 k3 = (i3 < NANCH) ? key[i3] : 0ull;
    u32 c0 = 0, c1 = 0, c2 = 0, c3 = 0;
    const ulonglong2* sk2 = (const ulonglong2*)sk;
#pragma unroll 5
    for (int j = 0; j < 250; ++j) {
        ulonglong2 v = sk2[j];
        c0 += (v.x < k0) ? 1u : 0u;  c0 += (v.y < k0) ? 1u : 0u;
        c1 += (v.x < k1) ? 1u : 0u;  c1 += (v.y < k1) ? 1u : 0u;
        c2 += (v.x < k2) ? 1u : 0u;  c2 += (v.y < k2) ? 1u : 0u;
        c3 += (v.x < k3) ? 1u : 0u;  c3 += (v.y < k3) ? 1u : 0u;
    }
    size_t base = (size_t)jb * NANCH;
    if (i0 < NANCH) rankp[base + i0] = c0;
    if (i1 < NANCH) rankp[base + i1] = c1;
    if (i2 < NANCH) rankp[base + i2] = c2;
    if (i3 < NANCH) rankp[base + i3] = c3;
}

// ---------------------------------------------------------------------------
// K3b: sum 45 partial ranks, scatter top-10000 (+ packed float4 boxes);
// sInv[r] = 1 if invalid box.
// ---------------------------------------------------------------------------
__global__ __launch_bounds__(256) void k3b_gather(const u32* __restrict__ rankp,
                                                  const float* __restrict__ score,
                                                  const float* __restrict__ bx1, const float* __restrict__ by1,
                                                  const float* __restrict__ bx2, const float* __restrict__ by2,
                                                  const u32* __restrict__ valid,
                                                  float* __restrict__ sS,
                                                  float* __restrict__ sx1, float* __restrict__ sy1,
                                                  float* __restrict__ sx2, float* __restrict__ sy2,
                                                  float4* __restrict__ sbox4,
                                                  u32* __restrict__ sInv)
{
    int i = blockIdx.x * 256 + threadIdx.x;
    if (i >= NANCH) return;
    u32 r = 0;
#pragma unroll
    for (int c = 0; c < NJC; ++c) r += rankp[(size_t)c * NANCH + i];
    if (r >= PRE_TOPK) return;
    float x1 = bx1[i], y1 = by1[i], x2 = bx2[i], y2 = by2[i];
    sS[r] = score[i];
    sx1[r] = x1; sy1[r] = y1; sx2[r] = x2; sy2[r] = y2;
    float4 b4; b4.x = x1; b4.y = y1; b4.z = x2; b4.w = y2;
    sbox4[r] = b4;
    sInv[r] = valid[i] ? 0u : 1u;
}

// ---------------------------------------------------------------------------
// K4 v6: row-per-wave suppression matrix + inline row zeroing (R19).
// The 12.8MB hipMemsetAsync existed only to zero (a) sub-diagonal words
// [0,wd) and (b) tail words 157..159 of each row (k5's commit reads words
// 0..159 of kept rows). Each wave owns its row -> zero those words inline
// (all 64 lanes, <=3 stores each) and drop the memset dispatch entirely.
// Bit-identical rows content at k5 entry.
// ---------------------------------------------------------------------------
__global__ __launch_bounds__(256) void k4_mat(const float4* __restrict__ sbox4,
                                              u64* __restrict__ rows,
                                              u64* __restrict__ selfw)
{
    int t = threadIdx.x, lane = t & 63, wave = t >> 6;
    int i = blockIdx.x * 4 + wave;
    if (i >= PRE_TOPK) return;
    float4 bi = sbox4[i];                       // wave-uniform, loaded once
    float ai = (bi.z - bi.x) * (bi.w - bi.y);
    int wd  = i >> 6;
    int ish = i & 63;
    u64 diagmask = ~((2ull << ish) - 1ull);     // ish=63 -> 0 (no j>i in word)
    u64* rowp = rows + (size_t)i * NWORDS;
    // zero sub-diagonal words [0,wd) and tail words 157..159 (lane-parallel)
    for (int w0 = lane; w0 < wd; w0 += 64) rowp[w0] = 0ull;
    if (lane < 3) rowp[157 + lane] = 0ull;
    for (int w = wd; w < 157; ++w) {
        float4 bj = sbox4[(w << 6) + lane];     // coalesced dwordx4
        float xx1 = fmaxf(bi.x, bj.x);
        float yy1 = fmaxf(bi.y, bj.y);
        float xx2 = fminf(bi.z, bj.z);
        float yy2 = fminf(bi.w, bj.w);
        float iw = fmaxf(xx2 - xx1, 0.f);
        float ih = fmaxf(yy2 - yy1, 0.f);
        float inter = iw * ih;
        float aj = (bj.z - bj.x) * (bj.w - bj.y);
        float uni = ai + aj - inter;
        u64 b = __ballot(inter > 0.7f * uni);
        if (w == wd)  b &= diagmask;
        if (w == 156) b &= 0xFFFFull;
        if (lane == 0) {
            rowp[w] = b;
            if (w == wd) selfw[i] = b;
        }
    }
}

// ---------------------------------------------------------------------------
// K5 v6 (R3-verified ~66us — FINAL): word-scan + scalar readlane resolve +
// batch-16 commit. R14/R15 restructures both regressed; latency-wait-bound
// at this structure (~58us structural floor of 157 serialized L2/L3 round
// trips). Do not touch.
// ---------------------------------------------------------------------------
__global__ __launch_bounds__(64) void k5_scan(const u64* __restrict__ rows,
                                              const u64* __restrict__ selfw,
                                              const u32* __restrict__ sInv,
                                              const float* __restrict__ sS,
                                              const float* __restrict__ sx1, const float* __restrict__ sy1,
                                              const float* __restrict__ sx2, const float* __restrict__ sy2,
                                              float* __restrict__ out)
{
    __shared__ int keptList[2000];
    __shared__ int kcnt;
    int l = threadIdx.x;
    auto bw = [&](int w) -> u64 {
        const uint4* p = (const uint4*)(sInv + (size_t)w * 64);
        u64 v = 0;
#pragma unroll
        for (int j = 0; j < 16; ++j) {
            uint4 q = p[j];
            v |= ((u64)(q.x != 0) << (j * 4))     | ((u64)(q.y != 0) << (j * 4 + 1))
               | ((u64)(q.z != 0) << (j * 4 + 2)) | ((u64)(q.w != 0) << (j * 4 + 3));
        }
        return v;
    };
    // 64-bit uniform readlane helper (2x v_readlane_b32)
    auto rdlane64 = [&](u64 v, int src) -> u64 {
        u32 lo = __builtin_amdgcn_readlane((u32)v, src);
        u32 hi = __builtin_amdgcn_readlane((u32)(v >> 32), src);
        return ((u64)hi << 32) | lo;
    };
    u64 r0 = bw(l);
    u64 r1 = bw(64 + l);
    u64 r2 = (l < 32) ? bw(128 + l) : ~0ull;

    // depth-8 selfw prefetch ring in named registers (static, no array)
    u64 s0 = selfw[(size_t)0 * 64 + l];
    u64 s1 = selfw[(size_t)1 * 64 + l];
    u64 s2 = selfw[(size_t)2 * 64 + l];
    u64 s3 = selfw[(size_t)3 * 64 + l];
    u64 s4 = selfw[(size_t)4 * 64 + l];
    u64 s5 = selfw[(size_t)5 * 64 + l];
    u64 s6 = selfw[(size_t)6 * 64 + l];
    u64 s7 = selfw[(size_t)7 * 64 + l];

    int cnt = 0;
    bool done = false;
    for (int w = 0; w < 157; ++w) {
        u64 swreg = s0;
        s0 = s1; s1 = s2; s2 = s3; s3 = s4; s4 = s5; s5 = s6; s6 = s7;
        s7 = (w + 8 < 157) ? selfw[(size_t)(w + 8) * 64 + l] : 0ull;

        int slot = w >> 6, owner = w & 63;
        u64 val = (slot == 0) ? r0 : (slot == 1) ? r1 : r2;
        u64 rw = rdlane64(val, owner);
        u64 wmask = (w == 156) ? 0xFFFFull : ~0ull;
        u64 av = (~rw) & wmask;

        // ---- intra-word greedy resolve: scalar chain via readlane ----
        u64 km = 0;
        while (av) {
            int b = __builtin_ctzll(av);
            u64 sw = rdlane64(swreg, b);
            km |= 1ull << b;
            av &= ~(1ull << b);
            av &= ~sw;
        }
        // ---- commit: OR kept rows in batches of 16 (loads back-to-back) ----
        u64 kk = km;
        while (kk) {
            int bsx[16];
            int nb = 0;
            while (kk && nb < 16) {
                int b = __builtin_ctzll(kk);
                kk &= kk - 1;
                bsx[nb++] = b;
            }
            u64 a0 = 0, a1 = 0, a2 = 0;
#pragma unroll
            for (int u = 0; u < 16; ++u) {
                if (u < nb) {
                    int i = (w << 6) + bsx[u];
                    if (l == 0 && cnt + u < 2000) keptList[cnt + u] = i;
                    const u64* rp = rows + (size_t)i * NWORDS;
                    a0 |= rp[l];
                    a1 |= rp[64 + l];
                    if (l < 32) a2 |= rp[128 + l];
                }
            }
            r0 |= a0; r1 |= a1; r2 |= a2;
            cnt += nb;
            if (cnt >= 2000) { done = true; break; }
        }
        if (done) break;
    }
    if (l == 0) kcnt = (cnt < 2000) ? cnt : 2000;
    __syncthreads();
    int K = kcnt;
    for (int r = l; r < 2000; r += 64) {
        if (r < K) {
            int j = keptList[r];
            out[r * 4 + 0] = sx1[j];
            out[r * 4 + 1] = sy1[j];
            out[r * 4 + 2] = sx2[j];
            out[r * 4 + 3] = sy2[j];
            out[8000 + r]  = sS[j];
        } else {
            out[r * 4 + 0] = 0.f; out[r * 4 + 1] = 0.f;
            out[r * 4 + 2] = 0.f; out[r * 4 + 3] = 0.f;
            out[8000 + r]  = 0.f;
        }
    }
}

// ---------------------------------------------------------------------------
extern "C" void kernel_launch(void* const* d_in, const int* in_sizes, int n_in,
                              void* d_out, int out_size, void* d_ws, size_t ws_size,
                              hipStream_t stream)
{
    (void)in_sizes; (void)n_in; (void)out_size;
    const float* feat = (const float*)d_in[1];
    const float* wrpn = (const float*)d_in[3];
    const float* brpn = (const float*)d_in[4];
    const float* wcls = (const float*)d_in[5];
    const float* bcls = (const float*)d_in[6];
    const float* wreg = (const float*)d_in[7];
    const float* breg = (const float*)d_in[8];
    float* out = (float*)d_out;

    // K-split factor by workspace budget. need(ns) = ns*512*2560*4 + 16,252,928.
    int ns = (ws_size >= 58195968) ? 8 : (ws_size >= 37224448) ? 4 : 2;
    int cpt     = 8 / ns;                 // 64c-chunks per tap per z-slice
    int cptLog  = (ns == 2) ? 2 : (ns == 4) ? 1 : 0;
    int cptm1   = cpt - 1;
    int cptMul  = cpt * 64;               // c0base = bs * cptMul
    int niter   = 9 * cpt;
    size_t pkB = (size_t)ns * 512 * 2560 * 4;

    char* ws = (char*)d_ws;
    // Live ranges:
    //   [0,pkB)            pk     k1m..k2a
    //   [pkB,pkB+16.25M)   Xt+W   kprep..k1m; then smalls (k2a+), part
    //                      (k2a..k2b), rankp (k3a..k3b, aliases part/rows
    //                      region — part dead after k2b, k4 writes after k3b),
    //                      rows (k4..k5) share offsets.
    float* pk = (float*)ws;
    unsigned short* Xthi = (unsigned short*)(ws + pkB);
    unsigned short* Xtlo = Xthi + (size_t)52 * 64 * 512;
    unsigned short* Whi  = (unsigned short*)(ws + pkB + 6815744);
    unsigned short* Wlo  = Whi + (size_t)512 * 4608;

    char* sm = ws + pkB;
    float* score = (float*)(sm + 0);             // 90,000
    float* bx1   = (float*)(sm + 90000);
    float* by1   = (float*)(sm + 180000);
    float* bx2   = (float*)(sm + 270000);
    float* by2   = (float*)(sm + 360000);
    u32*   valid = (u32*)  (sm + 450000);        // 90,000
    u64*   key   = (u64*)  (sm + 540000);        // 180,000
    float* sS    = (float*)(sm + 1620000);       // 40,000
    float* sx1   = (float*)(sm + 1660000);
    float* sy1   = (float*)(sm + 1700000);
    float* sx2   = (float*)(sm + 1740000);
    float* sy2   = (float*)(sm + 1780000);
    u32*   sInv  = (u32*)  (sm + 1820000);       // 40,960
    u64*   selfw = (u64*)  (sm + 1860960);       // 81,920
    float4* sbox4= (float4*)(sm + 1942880);      // 163,840 (10240 entries)
    float* part  = (float*)(sm + 2106720);       // 3,600,000 (k2a..k2b)
    u32*   rankp = (u32*)  (sm + 2106720);       // 4,050,000 (k3a..k3b; after part dead)
    u64*   rows  = (u64*)  (sm + 2106720);       // 12,800,000 (k4..k5) -> ends sm+14.91M < 16.25M
    // peak footprint = pkB + 16,252,928 (ns=4 -> 37.2 MB, proven available)

    AnchorBase ab;
    {
        const float scales[3] = {128.f, 256.f, 512.f};
        const float aspect[3] = {0.5f, 1.f, 2.f};
        for (int ai = 0; ai < 3; ++ai) {
            float hr = sqrtf(aspect[ai]);
            float wratio = 1.0f / hr;
            for (int si = 0; si < 3; ++si) {
                float wsz = wratio * scales[si];
                float hsz = hr * scales[si];
                int a = ai * 3 + si;
                ab.b[a * 4 + 0] = rintf(-wsz / 2.0f);
                ab.b[a * 4 + 1] = rintf(-hsz / 2.0f);
                ab.b[a * 4 + 2] = rintf( wsz / 2.0f);
                ab.b[a * 4 + 3] = rintf( hsz / 2.0f);
            }
        }
    }

    kprep    <<<928, 256, 0, stream>>>(feat, wrpn, Xthi, Xtlo, Whi, Wlo);
    k1m      <<<dim3(4, 40, ns), 256, 0, stream>>>(Xthi, Xtlo, Whi, Wlo, pk,
                                                   cptLog, cptm1, cptMul, niter);
    k2a_heads<<<dim3(40, 8), 256, 0, stream>>>(pk, ns, brpn, wcls, wreg, part);
    k2b_decode<<<88, 256, 0, stream>>>(part, bcls, breg, ab, score, bx1, by1, bx2, by2, valid, key);
    k3a_rank <<<dim3(22, NJC), 256, 0, stream>>>(key, rankp);
    k3b_gather<<<88, 256, 0, stream>>>(rankp, score, bx1, by1, bx2, by2, valid,
                                       sS, sx1, sy1, sx2, sy2, sbox4, sInv);
    k4_mat   <<<2500, 256, 0, stream>>>(sbox4, rows, selfw);   // zeroes its own rows
    k5_scan  <<<1, 64, 0, stream>>>(rows, selfw, sInv, sS, sx1, sy1, sx2, sy2, out);
}